// Round 8
// baseline (796.521 us; speedup 1.0000x reference)
//
#include <hip/hip_runtime.h>
#include <math.h>

// Correctness-critical invariant: kNN sets and eigenvectors must stay
// bit-identical to numpy/LAPACK (f32, contract off). The f64 feature path has
// large rounding slack (absmax 0.0 at threshold 6.7e-5) -> reassociation and
// f64 atomics are safe there. W f32->f64 conversion is exact.
//
// LESSON (r8-old): small-Q layers NEED the K-split grid dimension. Keep
// gemm's ksplit.
//
// LESSON (r2/r6): adding partitions per query multiplies tracker/merge work
// ~linearly; r6's 4-block split ran 78% busy but 1.66x instructions -> net
// regression. Utilization of existing work, not splits.
//
// LESSON (r7): hoisting the serial lane-0 geometry tail out of the Q=2435
// kNN kernels cut knng16 125->78us (and FETCH 15.6->2.2MB: the scattered
// posf reads were the HBM traffic). For SMALL Q the separate launch costs
// more than the parallel tail -> geom fused back only for Q<=181.
//
// THEORY (r8): remaining profile is flat (<78us steady) with a ~200us gap
// between kernel-sum and total -> ~30 launches x ~5-8us dispatch overhead.
// Cut launches: finalize folded into next t_kernel (fbias on read), geom
// re-fused for small-Q kNN (template keeps hot knng16 at VGPR 28), B3
// resid+head fused. Plus ksplit bumps (r4's proven lever): B1 48, B2 160,
// B3 320. 30 -> 25 launches.
#pragma clang fp contract(off)

// ---------------------------------------------------------------------------
__device__ __forceinline__ float f_sign(float a, float b) {
    return (b >= 0.0f) ? fabsf(a) : -fabsf(a);
}

__device__ float slapy2(float x, float y) {
    float xa = fabsf(x), ya = fabsf(y);
    float w = fmaxf(xa, ya), z = fminf(xa, ya);
    if (z == 0.0f) return w;
    float t = z / w;
    return w * sqrtf(1.0f + t * t);
}

__device__ void slartg(float f, float g, float &cs, float &sn, float &r) {
    if (g == 0.0f) { cs = 1.0f; sn = 0.0f; r = f; }
    else if (f == 0.0f) { cs = 0.0f; sn = f_sign(1.0f, g); r = fabsf(g); }
    else {
        float d = sqrtf(f * f + g * g);
        float p = 1.0f / d;
        cs = fabsf(f) * p;
        sn = g * f_sign(p, f);
        r = f_sign(d, f);
    }
}

__device__ void slaev2(float a, float b, float c,
                       float &rt1, float &rt2, float &cs1, float &sn1) {
    float sm = a + c, df = a - c, adf = fabsf(df), tb = b + b, ab = fabsf(tb);
    float acmx, acmn;
    if (fabsf(a) > fabsf(c)) { acmx = a; acmn = c; } else { acmx = c; acmn = a; }
    float rt;
    if (adf > ab) { float t = ab / adf; rt = adf * sqrtf(1.0f + t * t); }
    else if (adf < ab) { float t = adf / ab; rt = ab * sqrtf(1.0f + t * t); }
    else rt = ab * sqrtf(2.0f);
    int sgn1;
    if (sm < 0.0f) { rt1 = 0.5f * (sm - rt); sgn1 = -1; rt2 = (acmx / rt1) * acmn - (b / rt1) * b; }
    else if (sm > 0.0f) { rt1 = 0.5f * (sm + rt); sgn1 = 1; rt2 = (acmx / rt1) * acmn - (b / rt1) * b; }
    else { rt1 = 0.5f * rt; rt2 = -0.5f * rt; sgn1 = 1; }
    float cs; int sgn2;
    if (df >= 0.0f) { cs = df + rt; sgn2 = 1; } else { cs = df - rt; sgn2 = -1; }
    float acs = fabsf(cs);
    if (acs > ab) { float ct = -tb / cs; sn1 = 1.0f / sqrtf(1.0f + ct * ct); cs1 = ct * sn1; }
    else {
        if (ab == 0.0f) { cs1 = 1.0f; sn1 = 0.0f; }
        else { float tn = -cs / tb; cs1 = 1.0f / sqrtf(1.0f + tn * tn); sn1 = tn * cs1; }
    }
    if (sgn1 == sgn2) { float tn = cs1; cs1 = -sn1; sn1 = tn; }
}

// SSTEQR('I', n=3), f32-faithful.
__device__ void ssteqr3(float *d, float *e, float z[3][3]) {
    const int n = 3;
    const float eps = 5.9604644775390625e-08f;
    const float eps2 = eps * eps;
    const float safmin = 1.1754943508222875e-38f;
    for (int i = 0; i < 3; ++i)
        for (int j = 0; j < 3; ++j)
            z[i][j] = (i == j) ? 1.0f : 0.0f;
    const int nmaxit = n * 30;
    int jtot = 0;
    int l1 = 1;
    int l, m, lend;
    float p, g, r, c, s, f, b, rt1, rt2;
    float wc[2], wsn[2];

L10:
    if (l1 > n) goto L160;
    if (l1 > 1) e[l1 - 2] = 0.0f;
    if (l1 <= n - 1) {
        for (m = l1; m <= n - 1; ++m) {
            float tst = fabsf(e[m - 1]);
            if (tst == 0.0f) goto L30;
            if (tst <= (sqrtf(fabsf(d[m - 1])) * sqrtf(fabsf(d[m]))) * eps) {
                e[m - 1] = 0.0f;
                goto L30;
            }
        }
    }
    m = n;
L30:
    l = l1;
    lend = m;
    l1 = m + 1;
    if (lend == l) goto L10;
    {
        float anorm = 0.0f;
        for (int i = l; i <= lend; ++i) anorm = fmaxf(anorm, fabsf(d[i - 1]));
        for (int i = l; i <= lend - 1; ++i) anorm = fmaxf(anorm, fabsf(e[i - 1]));
        if (anorm == 0.0f) goto L10;
    }
    if (fabsf(d[lend - 1]) < fabsf(d[l - 1])) { int t = lend; lend = l; l = t; }

    if (lend > l) {
L40:
        if (l != lend) {
            bool found = false;
            for (m = l; m <= lend - 1; ++m) {
                float tst = e[m - 1] * e[m - 1];
                if (tst <= (eps2 * fabsf(d[m - 1])) * fabsf(d[m]) + safmin) { found = true; break; }
            }
            if (!found) m = lend;
        } else m = lend;
        if (m < lend) e[m - 1] = 0.0f;
        p = d[l - 1];
        if (m == l) goto L80;
        if (m == l + 1) {
            slaev2(d[l - 1], e[l - 1], d[l], rt1, rt2, c, s);
            for (int i = 0; i < n; ++i) {
                float tmp = z[i][l];
                z[i][l]     = c * tmp - s * z[i][l - 1];
                z[i][l - 1] = s * tmp + c * z[i][l - 1];
            }
            d[l - 1] = rt1; d[l] = rt2; e[l - 1] = 0.0f;
            l += 2;
            if (l <= lend) goto L40;
            goto L140;
        }
        if (jtot == nmaxit) goto L140;
        ++jtot;
        g = (d[l] - p) / (2.0f * e[l - 1]);
        r = slapy2(g, 1.0f);
        g = (d[m - 1] - p) + e[l - 1] / (g + f_sign(r, g));
        s = 1.0f; c = 1.0f; p = 0.0f;
        for (int i = m - 1; i >= l; --i) {
            f = s * e[i - 1];
            b = c * e[i - 1];
            slartg(g, f, c, s, r);
            if (i != m - 1) e[i] = r;
            g = d[i] - p;
            r = (d[i - 1] - g) * s + (2.0f * c) * b;
            p = s * r;
            d[i] = g + p;
            g = c * r - b;
            wc[i - 1] = c;
            wsn[i - 1] = -s;
        }
        for (int jj = m - 1; jj >= l; --jj) {
            float ct = wc[jj - 1], st = wsn[jj - 1];
            for (int i = 0; i < n; ++i) {
                float tmp = z[i][jj];
                z[i][jj]     = ct * tmp - st * z[i][jj - 1];
                z[i][jj - 1] = st * tmp + ct * z[i][jj - 1];
            }
        }
        d[l - 1] -= p;
        e[l - 1] = g;
        goto L40;
L80:
        d[l - 1] = p;
        ++l;
        if (l <= lend) goto L40;
        goto L140;
    } else {
L90:
        if (l != lend) {
            bool found = false;
            for (m = l; m >= lend + 1; --m) {
                float tst = e[m - 2] * e[m - 2];
                if (tst <= (eps2 * fabsf(d[m - 1])) * fabsf(d[m - 2]) + safmin) { found = true; break; }
            }
            if (!found) m = lend;
        } else m = lend;
        if (m > lend) e[m - 2] = 0.0f;
        p = d[l - 1];
        if (m == l) goto L130;
        if (m == l - 1) {
            slaev2(d[l - 2], e[l - 2], d[l - 1], rt1, rt2, c, s);
            for (int i = 0; i < n; ++i) {
                float tmp = z[i][l - 1];
                z[i][l - 1] = c * tmp - s * z[i][l - 2];
                z[i][l - 2] = s * tmp + c * z[i][l - 2];
            }
            d[l - 2] = rt1; d[l - 1] = rt2; e[l - 2] = 0.0f;
            l -= 2;
            if (l >= lend) goto L90;
            goto L140;
        }
        if (jtot == nmaxit) goto L140;
        ++jtot;
        g = (d[l - 2] - p) / (2.0f * e[l - 2]);
        r = slapy2(g, 1.0f);
        g = (d[m - 1] - p) + e[l - 2] / (g + f_sign(r, g));
        s = 1.0f; c = 1.0f; p = 0.0f;
        for (int i = m; i <= l - 1; ++i) {
            f = s * e[i - 1];
            b = c * e[i - 1];
            slartg(g, f, c, s, r);
            if (i != m) e[i - 2] = r;
            g = d[i - 1] - p;
            r = (d[i] - g) * s + (2.0f * c) * b;
            p = s * r;
            d[i - 1] = g + p;
            g = c * r - b;
            wc[i - 1] = c;
            wsn[i - 1] = s;
        }
        for (int jj = m; jj <= l - 1; ++jj) {
            float ct = wc[jj - 1], st = wsn[jj - 1];
            for (int i = 0; i < n; ++i) {
                float tmp = z[i][jj];
                z[i][jj]     = ct * tmp - st * z[i][jj - 1];
                z[i][jj - 1] = st * tmp + ct * z[i][jj - 1];
            }
        }
        d[l - 1] -= p;
        e[l - 2] = g;
        goto L90;
L130:
        d[l - 1] = p;
        --l;
        if (l >= lend) goto L90;
        goto L140;
    }
L140:
    if (jtot < nmaxit) goto L10;
L160:
    for (int ii = 2; ii <= n; ++ii) {
        int i = ii - 1, kk = i;
        float pp = d[i - 1];
        for (int j = ii; j <= n; ++j)
            if (d[j - 1] < pp) { kk = j; pp = d[j - 1]; }
        if (kk != i) {
            d[kk - 1] = d[i - 1];
            d[i - 1] = pp;
            for (int row = 0; row < n; ++row) {
                float t2 = z[row][i - 1];
                z[row][i - 1] = z[row][kk - 1];
                z[row][kk - 1] = t2;
            }
        }
    }
}

__device__ void ssyevd3(float a11, float a21, float a31,
                        float a22, float a32, float a33, float V[3][3]) {
    float tau1, v2, e1;
    float alpha = a21;
    float xnorm = fabsf(a31);
    if (xnorm == 0.0f) {
        tau1 = 0.0f; v2 = 0.0f; e1 = a21;
    } else {
        float beta = -f_sign(slapy2(alpha, xnorm), alpha);
        tau1 = (beta - alpha) / beta;
        float t = 1.0f / (alpha - beta);
        v2 = a31 * t;
        e1 = beta;
        float w1 = tau1 * a22;
        float w2 = tau1 * a32;
        float temp2 = a32 * v2;
        w1 = w1 + tau1 * temp2;
        float temp1 = tau1 * v2;
        w2 = w2 + temp1 * a33;
        float dot = w1;
        dot = dot + w2 * v2;
        float alpha2 = (-0.5f * tau1) * dot;
        w1 = w1 + alpha2;
        w2 = w2 + alpha2 * v2;
        a22 = (a22 - w1) - w1;
        a32 = (a32 - v2 * w1) - w2;
        a33 = (a33 - v2 * w2) - w2 * v2;
    }
    float d[3] = { a11, a22, a33 };
    float e[2] = { e1, a32 };
    float z[3][3];
    ssteqr3(d, e, z);
    for (int j = 0; j < 3; ++j) {
        float wj = z[1][j];
        wj = wj + z[2][j] * v2;
        float temp = (-tau1) * wj;
        V[0][j] = z[0][j];
        V[1][j] = z[1][j] + temp;
        V[2][j] = z[2][j] + v2 * temp;
    }
}

// Per-query geometry: r, scale, cov, ssyevd, rotate. Runs on one thread.
__device__ void geom_body(const float *__restrict__ posf, const int *__restrict__ ord,
                          int q, int k, float *__restrict__ rrot) {
    float qx = posf[3 * q], qy = posf[3 * q + 1], qz = posf[3 * q + 2];
    float rx[16], ry[16], rz[16], nrm[16];
    for (int j = 0; j < k; ++j) {
        int s = ord[j];
        rx[j] = posf[3 * s] - qx;
        ry[j] = posf[3 * s + 1] - qy;
        rz[j] = posf[3 * s + 2] - qz;
        float t = rx[j] * rx[j];
        t = t + ry[j] * ry[j];
        t = t + rz[j] * rz[j];
        nrm[j] = sqrtf(t);
    }
    float scale = nrm[0];
    for (int j = 1; j < k; ++j) scale = fmaxf(scale, nrm[j]);
    float sc = scale + 1e-8f;
    for (int j = 0; j < k; ++j) {
        rx[j] = rx[j] / sc;
        ry[j] = ry[j] / sc;
        rz[j] = rz[j] / sc;
    }
    float c00 = 0.f, c01 = 0.f, c02 = 0.f, c11 = 0.f, c12 = 0.f, c22 = 0.f;
    for (int j = 0; j < k; ++j) {
        c00 = c00 + rx[j] * rx[j];
        c01 = c01 + rx[j] * ry[j];
        c02 = c02 + rx[j] * rz[j];
        c11 = c11 + ry[j] * ry[j];
        c12 = c12 + ry[j] * rz[j];
        c22 = c22 + rz[j] * rz[j];
    }
    float fk = (float)k;
    c00 = c00 / fk; c01 = c01 / fk; c02 = c02 / fk;
    c11 = c11 / fk; c12 = c12 / fk; c22 = c22 / fk;
    float V[3][3];
    ssyevd3(c00, c01, c02, c11, c12, c22, V);
    for (int j = 0; j < k; ++j) {
        for (int col = 0; col < 3; ++col) {
            float a = rx[j] * V[0][col];
            a = a + ry[j] * V[1][col];
            a = a + rz[j] * V[2][col];
            rrot[q * 48 + j * 3 + col] = a;
        }
    }
}

// Standalone geometry: one THREAD per query (64 eigensolves per wave).
// Used for large-Q kNN calls (Q=2435) where the in-kernel serial tail is
// the bottleneck (r7: 125->78us).
__global__ __launch_bounds__(256) void geom_kernel(
    const float *__restrict__ posf, const int *__restrict__ idx,
    int Q, int k, float *__restrict__ rrot) {
    int q = blockIdx.x * 256 + threadIdx.x;
    if (q >= Q) return;
    geom_body(posf, idx + (size_t)q * k, q, k, rrot);
}

// ---------------------------------------------------------------------------

__global__ void prep_kernel(const float *__restrict__ posf, float4 *__restrict__ pos4) {
    int i = blockIdx.x * 256 + threadIdx.x;
    if (i >= 32768) return;
    float x = posf[3 * i], y = posf[3 * i + 1], z = posf[3 * i + 2];
    float t = x * x;
    t = t + y * y;
    t = t + z * z;
    pos4[i] = make_float4(x, y, z, t);
}

// Sorted-top-16 insert (lanes 0..15 hold the list ascending by (dist,idx)).
// No LDS-pipe ops: extracted candidate + kth via v_readlane (wave-uniform),
// list shift via DPP row_shr:1 (list lives entirely in row 0, lanes 0-15).
// Candidates arrive in increasing j within a wave, d==kth excluded,
// insert-after-equal -> identical semantics to reference lex top-16.
__device__ __forceinline__ void insert16(float d, int jbase, int lane,
                                         float &ld, int &li, float &kth) {
    unsigned long long mask = __ballot(d < kth);
    while (mask) {
        int src = __ffsll(mask) - 1;
        mask &= mask - 1;
        float dv = __int_as_float(__builtin_amdgcn_readlane(__float_as_int(d), src));
        int jv = jbase + src;
        if (dv < kth) {
            unsigned long long lm = __ballot((lane < 16) && (ld <= dv));
            int p2 = __popcll(lm);
            float sd = __int_as_float(__builtin_amdgcn_update_dpp(
                0, __float_as_int(ld), 0x111, 0xf, 0xf, true));
            int si = __builtin_amdgcn_update_dpp(0, li, 0x111, 0xf, 0xf, true);
            if (lane < 16) {
                if (lane == p2) { ld = dv; li = jv; }
                else if (lane > p2) { ld = sd; li = si; }
            }
            kth = __int_as_float(__builtin_amdgcn_readlane(__float_as_int(ld), 15));
        }
    }
}

// Init the top-16 list from 64 candidates via full 64-lane bitonic sort on
// lex key (dist, idx) ascending. Equivalent to sequentially inserting the 64
// distinct (d, jbase+lane) pairs into an empty list: lanes 0-15 = 16
// lex-smallest ascending; kth = lane 15. idx uniqueness -> total order.
__device__ __forceinline__ void sort64_init(float d, int jbase, int lane,
                                            float &ld, int &li, float &kth) {
    float v = d;
    int vi = jbase + lane;
#pragma unroll
    for (int k2 = 2; k2 <= 64; k2 <<= 1) {
#pragma unroll
        for (int j2 = k2 >> 1; j2 > 0; j2 >>= 1) {
            float ov = __shfl_xor(v, j2);
            int oi = __shfl_xor(vi, j2);
            bool oless = (ov < v) || (ov == v && oi < vi);
            bool dir = ((lane & k2) == 0);        // ascending block?
            bool keepmin = (((lane & j2) == 0) == dir);
            bool take = keepmin ? oless : !oless;
            if (take) { v = ov; vi = oi; }
        }
    }
    if (lane < 16) { ld = v; li = vi; }
    kth = __int_as_float(__builtin_amdgcn_readlane(__float_as_int(v), 15));
}

// Wave-level scan of candidate range [start,end) with prefetch + sort-init +
// pre-ballot tile skip. Returns per-wave sorted top-16 in (ld, li) lanes 0-15.
__device__ __forceinline__ void scan_range(
    const float4 *__restrict__ pos4, float4 qp, int start, int end, int lane,
    float &ld, int &li, float &kth) {
    const float FINF = 3.0e38f;
    int base = start;
    float4 c0, c1, c2, c3;
    bool have = (base + 256 <= end);
    bool first = true;
    if (have) {
        c0 = pos4[base + lane];
        c1 = pos4[base + 64 + lane];
        c2 = pos4[base + 128 + lane];
        c3 = pos4[base + 192 + lane];
    }
    while (have) {
        int nbase = base + 1024;
        bool nhave = (nbase + 256 <= end);
        float4 n0 = c0, n1 = c1, n2 = c2, n3 = c3;
        if (nhave) {
            n0 = pos4[nbase + lane];
            n1 = pos4[nbase + 64 + lane];
            n2 = pos4[nbase + 128 + lane];
            n3 = pos4[nbase + 192 + lane];
        }
        float m0 = fmaf(qp.x, c0.x, 0.0f);
        m0 = fmaf(qp.y, c0.y, m0);
        m0 = fmaf(qp.z, c0.z, m0);
        float d0 = (qp.w + c0.w) - 2.0f * m0;   // bit-identical reference sgemm form
        float m1 = fmaf(qp.x, c1.x, 0.0f);
        m1 = fmaf(qp.y, c1.y, m1);
        m1 = fmaf(qp.z, c1.z, m1);
        float d1 = (qp.w + c1.w) - 2.0f * m1;
        float m2 = fmaf(qp.x, c2.x, 0.0f);
        m2 = fmaf(qp.y, c2.y, m2);
        m2 = fmaf(qp.z, c2.z, m2);
        float d2 = (qp.w + c2.w) - 2.0f * m2;
        float m3 = fmaf(qp.x, c3.x, 0.0f);
        m3 = fmaf(qp.y, c3.y, m3);
        m3 = fmaf(qp.z, c3.z, m3);
        float d3 = (qp.w + c3.w) - 2.0f * m3;
        // Pre-ballot tile skip: kth only tightens, so if no lane's min
        // passes now, none of the 4 sub-tiles can insert. Semantics equal.
        float dmin = fminf(fminf(d0, d1), fminf(d2, d3));
        if (first || __ballot(dmin < kth)) {
            if (first) {
                sort64_init(d0, base, lane, ld, li, kth);
                first = false;
            } else {
                insert16(d0, base, lane, ld, li, kth);
            }
            insert16(d1, base + 64, lane, ld, li, kth);
            insert16(d2, base + 128, lane, ld, li, kth);
            insert16(d3, base + 192, lane, ld, li, kth);
        }
        c0 = n0; c1 = n1; c2 = n2; c3 = n3;
        base = nbase;
        have = nhave;
    }
    if (base < end) {
#pragma unroll
        for (int k2 = 0; k2 < 4; ++k2) {
            int j = base + k2 * 64 + lane;
            float dd = FINF;
            if (j < end) {
                float4 p = pos4[j];
                float m = fmaf(qp.x, p.x, 0.0f);
                m = fmaf(qp.y, p.y, m);
                m = fmaf(qp.z, p.z, m);
                dd = (qp.w + p.w) - 2.0f * m;
            }
            insert16(dd, base + k2 * 64, lane, ld, li, kth);
        }
    }
}

// Two-stage bitonic merge of four sorted 16-lists (md/mi[64]) -> sorted 16
// in lanes 0-15 (v2, vi2). Lex key (dist,idx) ascending. r1-verified.
__device__ __forceinline__ void merge4x16(const float *md, const int *mi,
                                          int lane, float &v2, int &vi2) {
    int l16 = lane & 15;
    int srcA = (lane >> 5) * 32 + ((lane & 16) ? (16 + (15 - l16)) : l16);
    float v = md[srcA];
    int vi = mi[srcA];
    for (int off = 16; off > 0; off >>= 1) {
        float ov = __shfl_xor(v, off);
        int oi = __shfl_xor(vi, off);
        bool oless = (ov < v) || (ov == v && oi < vi);
        bool take = (lane & off) ? (!oless) : oless;
        if (take) { v = ov; vi = oi; }
    }
    int src2 = (lane < 16) ? lane : (63 - lane);
    v2 = __shfl(v, src2);
    vi2 = __shfl(vi, src2);
    for (int off = 16; off > 0; off >>= 1) {
        float ov = __shfl_xor(v2, off);
        int oi = __shfl_xor(vi2, off);
        bool oless = (ov < v2) || (ov == v2 && oi < vi2);
        bool take = (lane & off) ? (!oless) : oless;
        if (take) { v2 = ov; vi2 = oi; }
    }
}

// k=16 kNN. 1 query/block, 4 waves, 4 candidates/lane/iter; wave w scans
// base=w*256 stride 1024 -- identical candidate partition/order to the
// verified r5 kernel. DOGEOM=1 instantiation (small Q) runs the lane-0
// geometry tail in-block; DOGEOM=0 (hot large-Q path) stays lean (VGPR 28).
template <int DOGEOM>
__global__ __launch_bounds__(256) void knng16_kernel(
    const float4 *__restrict__ pos4, const float *__restrict__ posf,
    int S, int *__restrict__ idx_out, float *__restrict__ rrot) {
    __shared__ float md[64];
    __shared__ int mi[64];
    __shared__ int ord[16];
    int q = blockIdx.x;
    int tid = threadIdx.x;
    int lane = tid & 63;
    int w = tid >> 6;
    float4 qp = pos4[q];
    const float FINF = 3.0e38f;
    float ld = FINF;
    int li = 0x7fffffff;
    float kth = FINF;
    scan_range(pos4, qp, w * 256, S, lane, ld, li, kth);
    if (lane < 16) { md[w * 16 + lane] = ld; mi[w * 16 + lane] = li; }
    __syncthreads();
    if (w == 0) {
        float v2; int vi2;
        merge4x16(md, mi, lane, v2, vi2);
        if (lane < 16) {
            idx_out[q * 16 + lane] = vi2;
            if (DOGEOM) ord[lane] = vi2;
        }
        if (DOGEOM && lane == 0) geom_body(posf, ord, q, 16, rrot);
    }
}

// Small-S (S <= 64) kNN + in-block geometry; one wave per query (small Q).
__global__ __launch_bounds__(64) void knngs_kernel(
    const float4 *__restrict__ pos4, const float *__restrict__ posf,
    int S, int k, int *__restrict__ idx_out, float *__restrict__ rrot) {
    __shared__ int ord[16];
    int q = blockIdx.x;
    int lane = threadIdx.x;
    float4 qp = pos4[q];
    const float FINF = 3.0e38f;
    float dist = FINF;
    if (lane < S) {
        float4 p = pos4[lane];
        float m = fmaf(qp.x, p.x, 0.0f);
        m = fmaf(qp.y, p.y, m);
        m = fmaf(qp.z, p.z, m);
        dist = (qp.w + p.w) - 2.0f * m;
    }
    bool used = false;
    for (int r = 0; r < k; ++r) {
        float v = used ? FINF : dist;
        int vid = (used || lane >= S) ? 0x7fffffff : lane;
        for (int off = 32; off > 0; off >>= 1) {
            float ov = __shfl_down(v, off);
            int oid = __shfl_down(vid, off);
            if (ov < v || (ov == v && oid < vid)) { v = ov; vid = oid; }
        }
        vid = __shfl(vid, 0);
        if (lane == 0) { idx_out[q * k + r] = vid; ord[r] = vid; }
        if (lane == vid) used = true;
    }
    if (lane == 0) geom_body(posf, ord, q, k, rrot);
}

__device__ __forceinline__ void compute_phi(const float *rrot, int q, int tid,
                                            double phi[45]) {
    double x = (double)rrot[q * 48 + tid * 3 + 0];
    double y = (double)rrot[q * 48 + tid * 3 + 1];
    double z = (double)rrot[q * 48 + tid * 3 + 2];
    double px[5], py[3], pz[3];
    px[0] = 1.0; px[1] = x; px[2] = x * x; px[3] = px[2] * x; px[4] = px[3] * x;
    py[0] = 1.0; py[1] = y; py[2] = y * y;
    pz[0] = 1.0; pz[1] = z; pz[2] = z * z;
#pragma unroll
    for (int n2 = 0; n2 < 5; ++n2)
#pragma unroll
        for (int l2 = 0; l2 < 3; ++l2)
#pragma unroll
            for (int m2 = 0; m2 < 3; ++m2)
                phi[n2 * 9 + l2 * 3 + m2] = (px[n2] * py[l2]) * pz[m2];
}

// Generic per-query fused conv (B0-L1, C=4).
__global__ __launch_bounds__(256) void feat_kernel(
    const float *__restrict__ rrot, const int *__restrict__ idx, int k,
    const double *__restrict__ fin64, const float *__restrict__ fin32, int C,
    const float *__restrict__ W, const float *__restrict__ bias, int O,
    double *__restrict__ fout) {
    __shared__ double phi_sh[16][45];
    __shared__ int idx_sh[16];
    __shared__ double red_sh[256];
    extern __shared__ double dyn[];
    double *nf = dyn;            // [16][C]
    double *t = dyn + 16 * C;    // [9][C]
    int q = blockIdx.x;
    int tid = threadIdx.x;
    int OT = O < 256 ? O : 256;
    int nseg = 256 / OT;
    int o = tid % OT;
    int seg = tid / OT;
    int cseg = C / nseg;
    int c0 = seg * cseg, c1 = c0 + cseg;
    if (tid < k) {
        idx_sh[tid] = idx[q * k + tid];
        double phi[45];
        compute_phi(rrot, q, tid, phi);
#pragma unroll
        for (int b2 = 0; b2 < 45; ++b2) phi_sh[tid][b2] = phi[b2];
    }
    __syncthreads();
    for (int e2 = tid; e2 < k * C; e2 += 256) {
        int j = e2 / C, cc = e2 - j * C;
        size_t src = (size_t)idx_sh[j] * C + cc;
        nf[j * C + cc] = fin32 ? (double)fin32[src] : fin64[src];
    }
    __syncthreads();
    double accp = 0.0;
    for (int ch = 0; ch < 45; ch += 9) {
        for (int e2 = tid; e2 < 9 * C; e2 += 256) {
            int b2 = e2 / C, cc = e2 - b2 * C;
            double a2 = 0.0;
            for (int j = 0; j < k; ++j) a2 = fma(phi_sh[j][ch + b2], nf[j * C + cc], a2);
            t[e2] = a2 / (double)k;
        }
        __syncthreads();
        double a0 = 0.0, a1 = 0.0;
        for (int b2 = 0; b2 < 9; ++b2) {
            const float *wp = W + (size_t)(ch + b2) * C * O + o;
            const double *tp = t + b2 * C;
            int cc = c0;
            for (; cc + 2 <= c1; cc += 2) {
                a0 = fma(tp[cc],     (double)wp[(size_t)cc * O], a0);
                a1 = fma(tp[cc + 1], (double)wp[(size_t)(cc + 1) * O], a1);
            }
            for (; cc < c1; ++cc) a0 = fma(tp[cc], (double)wp[(size_t)cc * O], a0);
        }
        accp += a0 + a1;
        __syncthreads();
    }
    red_sh[tid] = accp;
    __syncthreads();
    if (tid < OT) {
        double v = 0.0;
        for (int s2 = 0; s2 < nseg; ++s2) v += red_sh[tid + s2 * OT];
        v += (double)bias[tid];
        fout[(size_t)q * O + tid] = v > 0.0 ? v : 0.0;
    }
}

// Specialized C=64, O=64, k=16 fused conv (B0-L2), 2 queries per block.
__global__ __launch_bounds__(256) void feat64_kernel(
    const float *__restrict__ rrot, const int *__restrict__ idx,
    const double *__restrict__ fin, const float *__restrict__ W,
    const float *__restrict__ bias, int Q, double *__restrict__ fout) {
    __shared__ double phi_sh[2][16][45];
    __shared__ int idx_sh[2][16];
    __shared__ double nf[2][16][64];
    __shared__ double t[2][9][64];
    __shared__ double red[16][64];
    int q0 = blockIdx.x * 2;
    int nq = (Q - q0) < 2 ? (Q - q0) : 2;
    int tid = threadIdx.x;
    int tx = tid & 15;
    int seg = tid >> 4;
    int o0 = tx * 4;
    int cbase = seg * 4;
    if (tid < 32) {
        int qi = tid >> 4, j = tid & 15;
        int qq = q0 + (qi < nq ? qi : 0);
        idx_sh[qi][j] = idx[qq * 16 + j];
        double phi[45];
        compute_phi(rrot, qq, j, phi);
#pragma unroll
        for (int b2 = 0; b2 < 45; ++b2) phi_sh[qi][j][b2] = phi[b2];
    }
    __syncthreads();
    for (int e2 = tid; e2 < 2 * 16 * 64; e2 += 256) {
        int qi = e2 >> 10, j = (e2 >> 6) & 15, cc = e2 & 63;
        nf[qi][j][cc] = fin[(size_t)idx_sh[qi][j] * 64 + cc];
    }
    __syncthreads();
    double acc[2][4] = {{0.0, 0.0, 0.0, 0.0}, {0.0, 0.0, 0.0, 0.0}};
    for (int ch = 0; ch < 45; ch += 9) {
        for (int e2 = tid; e2 < 2 * 9 * 64; e2 += 256) {
            int qi = e2 / 576, rem = e2 - qi * 576;
            int b2 = rem >> 6, cc = rem & 63;
            double a2 = 0.0;
#pragma unroll
            for (int j = 0; j < 16; ++j) a2 = fma(phi_sh[qi][j][ch + b2], nf[qi][j][cc], a2);
            t[qi][b2][cc] = a2 * 0.0625;
        }
        __syncthreads();
#pragma unroll
        for (int b2 = 0; b2 < 9; ++b2) {
            const float *wrow = W + ((size_t)(ch + b2) * 64 + cbase) * 64 + o0;
#pragma unroll
            for (int i = 0; i < 4; ++i) {
                float4 wv = *(const float4 *)(wrow + (size_t)i * 64);
                double w0 = (double)wv.x, w1 = (double)wv.y;
                double w2 = (double)wv.z, w3 = (double)wv.w;
                double tv0 = t[0][b2][cbase + i];
                double tv1 = t[1][b2][cbase + i];
                acc[0][0] = fma(tv0, w0, acc[0][0]);
                acc[0][1] = fma(tv0, w1, acc[0][1]);
                acc[0][2] = fma(tv0, w2, acc[0][2]);
                acc[0][3] = fma(tv0, w3, acc[0][3]);
                acc[1][0] = fma(tv1, w0, acc[1][0]);
                acc[1][1] = fma(tv1, w1, acc[1][1]);
                acc[1][2] = fma(tv1, w2, acc[1][2]);
                acc[1][3] = fma(tv1, w3, acc[1][3]);
            }
        }
        __syncthreads();
    }
    for (int qi = 0; qi < nq; ++qi) {
        red[seg][o0 + 0] = acc[qi][0];
        red[seg][o0 + 1] = acc[qi][1];
        red[seg][o0 + 2] = acc[qi][2];
        red[seg][o0 + 3] = acc[qi][3];
        __syncthreads();
        if (tid < 64) {
            double v = 0.0;
#pragma unroll
            for (int s2 = 0; s2 < 16; ++s2) v += red[s2][tid];
            v += (double)bias[tid];
            fout[(size_t)(q0 + qi) * 64 + tid] = v > 0.0 ? v : 0.0;
        }
        __syncthreads();
    }
}

// Stage 1 (small Q): t[q-q0][45*C], grid (qcount, 5 basis chunks of 9).
// blockIdx.y==0 blocks also zero this q's fout row (replaces hipMemsetAsync;
// gemm's atomics run in a strictly later kernel, so no race).
// fbias != nullptr: fin holds the previous gemm's RAW accumulator; apply
// v = relu(fin + bias) on read -- identical f64 op order to the removed
// finalize_kernel pass.
__global__ __launch_bounds__(256) void t_kernel(
    const float *__restrict__ rrot, const int *__restrict__ idx, int k,
    const double *__restrict__ fin, const float *__restrict__ fbias, int C,
    int q0, double *__restrict__ tbuf, double *__restrict__ fout, int O) {
    __shared__ double phi_sh[16][45];
    __shared__ int idx_sh[16];
    extern __shared__ double nf[];  // [16][C]
    int q = q0 + blockIdx.x;
    int bch = blockIdx.y * 9;
    int tid = threadIdx.x;
    if (blockIdx.y == 0) {
        for (int i = tid; i < O; i += 256) fout[(size_t)q * O + i] = 0.0;
    }
    if (tid < k) {
        idx_sh[tid] = idx[q * k + tid];
        double phi[45];
        compute_phi(rrot, q, tid, phi);
#pragma unroll
        for (int b2 = 0; b2 < 45; ++b2) phi_sh[tid][b2] = phi[b2];
    }
    __syncthreads();
    for (int e2 = tid; e2 < k * C; e2 += 256) {
        int j = e2 / C, cc = e2 - j * C;
        double v = fin[(size_t)idx_sh[j] * C + cc];
        if (fbias) {
            v = v + (double)fbias[cc];
            v = v > 0.0 ? v : 0.0;
        }
        nf[j * C + cc] = v;
    }
    __syncthreads();
    int K = 45 * C;
    for (int e2 = tid; e2 < 9 * C; e2 += 256) {
        int b2 = bch + e2 / C, cc = e2 % C;
        double a2 = 0.0;
        for (int j = 0; j < k; ++j) a2 = fma(phi_sh[j][b2], nf[j * C + cc], a2);
        tbuf[(size_t)blockIdx.x * K + b2 * C + cc] = a2 / (double)k;
    }
}

// Stage 2: K-split GEMM, f64 atomics straight into acc (= fout region).
// Unroll-8, 8 independent accumulators, double2 tp loads (tbuf 16B-aligned,
// kchunk forced to a multiple of 8 by the launcher).
__global__ __launch_bounds__(256) void gemm_kernel(
    const double *__restrict__ tbuf, const float *__restrict__ W,
    int K, int O, int q0, int q1, int kchunk, double *__restrict__ acc) {
    int OT = O < 256 ? O : 256;
    int qpb = 256 / OT;
    int tid = threadIdx.x;
    int o = blockIdx.x * OT + (tid % OT);
    int q = q0 + blockIdx.y * qpb + tid / OT;
    if (q >= q1) return;
    int k0 = blockIdx.z * kchunk;
    if (k0 >= K) return;
    int kend = min(k0 + kchunk, K);
    const double *tp = tbuf + (size_t)(q - q0) * K;
    const float *wp = W + (size_t)k0 * O + o;
    double a0 = 0.0, a1 = 0.0, a2 = 0.0, a3 = 0.0;
    double a4 = 0.0, a5 = 0.0, a6 = 0.0, a7 = 0.0;
    int kk = k0;
    for (; kk + 8 <= kend; kk += 8) {
        double2 t01 = *(const double2 *)(tp + kk);
        double2 t23 = *(const double2 *)(tp + kk + 2);
        double2 t45 = *(const double2 *)(tp + kk + 4);
        double2 t67 = *(const double2 *)(tp + kk + 6);
        float w0 = wp[0];
        float w1 = wp[(size_t)O];
        float w2 = wp[2 * (size_t)O];
        float w3 = wp[3 * (size_t)O];
        float w4 = wp[4 * (size_t)O];
        float w5 = wp[5 * (size_t)O];
        float w6 = wp[6 * (size_t)O];
        float w7 = wp[7 * (size_t)O];
        a0 = fma(t01.x, (double)w0, a0);
        a1 = fma(t01.y, (double)w1, a1);
        a2 = fma(t23.x, (double)w2, a2);
        a3 = fma(t23.y, (double)w3, a3);
        a4 = fma(t45.x, (double)w4, a4);
        a5 = fma(t45.y, (double)w5, a5);
        a6 = fma(t67.x, (double)w6, a6);
        a7 = fma(t67.y, (double)w7, a7);
        wp += 8 * (size_t)O;
    }
    for (; kk < kend; ++kk) {
        a0 = fma(tp[kk], (double)wp[0], a0);
        wp += (size_t)O;
    }
    double s = ((a0 + a1) + (a2 + a3)) + ((a4 + a5) + (a6 + a7));
    atomicAdd(&acc[(size_t)q * O + o], s);
}

__global__ void resid0_kernel(const float *__restrict__ chanf, const float *__restrict__ p,
                              const double *__restrict__ x, double *__restrict__ fout) {
    int i = blockIdx.x * 256 + threadIdx.x;
    if (i >= 2435 * 64) return;
    int q = i >> 6, o = i & 63;
    const float *f = chanf + 4 * q;
    float c = fmaf(f[0], p[o], 0.0f);
    c = fmaf(f[1], p[64 + o], c);
    c = fmaf(f[2], p[128 + o], c);
    c = fmaf(f[3], p[192 + o], c);
    double v = x[i] + (double)c;
    fout[i] = v > 0.0 ? v : 0.0;
}

// Fused finalize + residual: x = relu(acc + bias); fout = relu(x + fin@p).
// Identical op order to finalize followed by the residual pass.
__global__ void resid64f_kernel(const float *__restrict__ bias,
                                const double *__restrict__ acc,
                                const double *__restrict__ fin, int Cin,
                                const float *__restrict__ p,
                                int Q, int Cout, double *__restrict__ fout) {
    int i = blockIdx.x * blockDim.x + threadIdx.x;
    if (i >= Q * Cout) return;
    int q = i / Cout, o = i - q * Cout;
    double v = acc[i] + (double)bias[o];
    double x = v > 0.0 ? v : 0.0;
    double a = 0.0;
    for (int c = 0; c < Cin; ++c) a = fma(fin[q * Cin + c], (double)p[c * Cout + o], a);
    double r = x + a;
    fout[i] = r > 0.0 ? r : 0.0;
}

// B3 tail: fused finalize + residual (Q=1, Cout=512) + head dot product.
// Per-element math identical to resid64f; final f64 dot is tree-reduced
// (f64 slack covers reassociation; output threshold 6.7e-5).
__global__ __launch_bounds__(512) void resid_head_kernel(
    const float *__restrict__ bias, const double *__restrict__ acc,
    const double *__restrict__ fin, int Cin, const float *__restrict__ p,
    const float *__restrict__ hw, const float *__restrict__ hb,
    float *__restrict__ out) {
    __shared__ double rv[512];
    __shared__ double red[64];
    int i = threadIdx.x;
    double v = acc[i] + (double)bias[i];
    double x = v > 0.0 ? v : 0.0;
    double a = 0.0;
    for (int c = 0; c < Cin; ++c) a = fma(fin[c], (double)p[c * 512 + i], a);
    double r = x + a;
    r = r > 0.0 ? r : 0.0;
    rv[i] = r * (double)hw[i];
    __syncthreads();
    if (i < 64) {
        double s = 0.0;
        for (int j = 0; j < 8; ++j) s += rv[i * 8 + j];
        red[i] = s;
    }
    __syncthreads();
    if (i == 0) {
        double s = 0.0;
        for (int j = 0; j < 64; ++j) s += red[j];
        out[0] = (float)(s + (double)hb[0]);
    }
}

// ---------------------------------------------------------------------------

extern "C" void kernel_launch(void *const *d_in, const int *in_sizes, int n_in,
                              void *d_out, int out_size, void *d_ws, size_t ws_size,
                              hipStream_t stream) {
    (void)in_sizes; (void)n_in; (void)out_size;

    const float *posf = (const float *)d_in[0];
    const float *chanf = (const float *)d_in[1];
    const float *W[8], *B[8];
    for (int li = 1; li <= 7; ++li) {
        W[li] = (const float *)d_in[2 + 2 * (li - 1)];
        B[li] = (const float *)d_in[3 + 2 * (li - 1)];
    }
    const float *P[5];
    for (int bi = 1; bi <= 4; ++bi) P[bi] = (const float *)d_in[15 + bi];
    const float *hw = (const float *)d_in[20];
    const float *hb = (const float *)d_in[21];

    // workspace layout (bytes)
    char *wsb = (char *)d_ws;
    double *B1   = (double *)(wsb + 0);            // 2435*64 f64 = 1,246,720
    double *B2   = (double *)(wsb + 1246720);
    double *B3   = (double *)(wsb + 2493440);
    float *rrot  = (float *)(wsb + 3740160);       // 2435*48 f32 = 467,520
    int *idx     = (int *)(wsb + 4207680);         // 2435*16 = 155,840
    float4 *pos4 = (float4 *)(wsb + 4363520);      // 32768*16 = 524,288
    double *tbuf = (double *)(wsb + 4887808);      // 4 MB (small-Q chunks)
    if (ws_size < 9082112) return;

    prep_kernel<<<128, 256, 0, stream>>>(posf, pos4);

    // Large Q: selection-only kNN + parallel geom kernel (r7 win).
    // Small Q: geometry fused in-block (launch overhead > parallel tail).
    auto knng = [&](int Q, int S, int k) {
        if (S <= 64) {
            knngs_kernel<<<Q, 64, 0, stream>>>(pos4, posf, S, k, idx, rrot);
        } else if (Q >= 512) {
            knng16_kernel<0><<<Q, 256, 0, stream>>>(pos4, posf, S, idx, rrot);
            geom_kernel<<<(Q + 255) / 256, 256, 0, stream>>>(posf, idx, Q, k, rrot);
        } else {
            knng16_kernel<1><<<Q, 256, 0, stream>>>(pos4, posf, S, idx, rrot);
        }
    };

    // fused per-query path (B0-L1)
    auto conv = [&](int Q, int S, int k, const double *fin64, const float *fin32, int C,
                    const float *w, const float *bias, int O, double *fout) {
        knng(Q, S, k);
        size_t dyn = (size_t)(16 + 9) * C * sizeof(double);
        feat_kernel<<<Q, 256, dyn, stream>>>(rrot, idx, k, fin64, fin32, C, w, bias, O, fout);
    };

    // specialized C=64/O=64 path (B0-L2)
    auto conv64 = [&](int Q, int S, const double *fin, const float *w,
                      const float *bias, double *fout) {
        knng(Q, S, 16);
        feat64_kernel<<<(Q + 1) / 2, 256, 0, stream>>>(rrot, idx, fin, w, bias, Q, fout);
    };

    // split t + K-parallel GEMM path (small Q) -- K-split grid is essential.
    // fout is left as RAW atomic acc; the layer's bias+relu is applied by
    // the consumer (next t_kernel's fbias, or resid64f/resid_head).
    // fbias: bias of the layer that produced fin, when fin is raw acc.
    auto conv2 = [&](int Q, int S, int k, const double *fin, const float *fbias,
                     int C, const float *w, int O, double *fout,
                     int ksplit, bool skip_knn) {
        if (!skip_knn) knng(Q, S, k);
        int K = 45 * C;
        int qc = 4194304 / (K * 8);
        if (qc > Q) qc = Q;
        int OT = O < 256 ? O : 256;
        int qpb = 256 / OT;
        int kchunk = (((K + ksplit - 1) / ksplit) + 7) & ~7;
        for (int q0 = 0; q0 < Q; q0 += qc) {
            int qn = min(qc, Q - q0);
            dim3 gt(qn, 5);
            t_kernel<<<gt, 256, (size_t)16 * C * sizeof(double), stream>>>(
                rrot, idx, k, fin, fbias, C, q0, tbuf, fout, O);
            dim3 g(O / OT, (qn + qpb - 1) / qpb, ksplit);
            gemm_kernel<<<g, 256, 0, stream>>>(tbuf, w, K, O, q0, q0 + qn, kchunk, fout);
        }
    };

    // Block 0 (Q=2435)
    conv(2435, 32768, 16, nullptr, chanf, 4, W[1], B[1], 64, B1);
    conv64(2435, 2435, B1, W[2], B[2], B2);
    resid0_kernel<<<(2435 * 64 + 255) / 256, 256, 0, stream>>>(chanf, P[1], B2, B3);
    // Block 1 (Q=181)
    // L3 kNN == rows 0..180 of B0-L2's knn(pos[:2435],pos[:2435]) -> skip.
    conv2(181, 2435, 16, B3, nullptr, 64, W[3], 128, B1, 48, true);
    // L4: fin = L3's raw acc -> fbias = B[3].
    conv2(181, 181, 16, B1, B[3], 128, W[4], 128, B2, 48, false);
    resid64f_kernel<<<(181 * 128 + 255) / 256, 256, 0, stream>>>(
        B[4], B2, B3, 64, P[2], 181, 128, B1);
    // Block 2 (Q=13)
    // L5 kNN == rows 0..12 of B1-L4's knn(pos[:181],pos[:181]) -> skip.
    conv2(13, 181, 16, B1, nullptr, 128, W[5], 256, B2, 160, true);
    // L6: fin = L5's raw acc -> fbias = B[5].
    conv2(13, 13, 13, B2, B[5], 256, W[6], 256, B3, 160, false);
    resid64f_kernel<<<(13 * 256 + 255) / 256, 256, 0, stream>>>(
        B[6], B3, B1, 128, P[3], 13, 256, B2);
    // Block 3 (Q=1)
    // L7 kNN == row 0 of B2-L6's knn(pos[:13],pos[:13],k=13) -> skip.
    conv2(1, 13, 13, B2, nullptr, 256, W[7], 512, B1, 320, true);
    // Fused B3 residual + head.
    resid_head_kernel<<<1, 512, 0, stream>>>(B[7], B1, B2, 256, P[4], hw, hb,
                                             (float *)d_out);
}

// Round 9
// 750.776 us; speedup vs baseline: 1.0609x; 1.0609x over previous
//
#include <hip/hip_runtime.h>
#include <math.h>

// Correctness-critical invariant: kNN sets and eigenvectors must stay
// bit-identical to numpy/LAPACK (f32, contract off). The f64 feature path has
// large rounding slack (absmax 0.0 at threshold 6.7e-5) -> reassociation and
// f64 atomics are safe there. W f32->f64 conversion is exact.
//
// LESSON (r8-old): small-Q layers NEED the K-split grid dimension.
// LESSON (r2/r6): partitions per query multiply tracker work ~linearly;
// utilization of existing work, not splits.
// LESSON (r7): serial lane-0 geometry tail hoisted out of hot kNN ->
// 125->78us, FETCH 15.6->2.2MB. Small-Q keeps fused geom.
// LESSON (r8): launch-count cuts were ~neutral; the REAL tail cost surfaced:
// resid_head (1 block, B3 tail) = ~100us steady at VALUBusy 0.009% -- pure
// load-latency serialization on one CU (256 strided p-loads/thread, ~8 waves
// of MLP vs ~900cy misses). ~12.5% of total for 131k FMAs.
//
// THEORY (r9): parallelize the B3 tail: rvdot_kernel (8 blocks x 256thr,
// 4 thr/output, coalesced p reads, LDS reduce, f64 atomicAdd of r.hw into an
// 8-byte scalar) + outhead_kernel (1 thread: scalar+hb -> f32). Scalar lives
// in the last 8B of tbuf (never written: B1 t-chunks <= 4MB-1024) and is
// zeroed by prep_kernel at stream start. f64 reassociation within slack.
#pragma clang fp contract(off)

// ---------------------------------------------------------------------------
__device__ __forceinline__ float f_sign(float a, float b) {
    return (b >= 0.0f) ? fabsf(a) : -fabsf(a);
}

__device__ float slapy2(float x, float y) {
    float xa = fabsf(x), ya = fabsf(y);
    float w = fmaxf(xa, ya), z = fminf(xa, ya);
    if (z == 0.0f) return w;
    float t = z / w;
    return w * sqrtf(1.0f + t * t);
}

__device__ void slartg(float f, float g, float &cs, float &sn, float &r) {
    if (g == 0.0f) { cs = 1.0f; sn = 0.0f; r = f; }
    else if (f == 0.0f) { cs = 0.0f; sn = f_sign(1.0f, g); r = fabsf(g); }
    else {
        float d = sqrtf(f * f + g * g);
        float p = 1.0f / d;
        cs = fabsf(f) * p;
        sn = g * f_sign(p, f);
        r = f_sign(d, f);
    }
}

__device__ void slaev2(float a, float b, float c,
                       float &rt1, float &rt2, float &cs1, float &sn1) {
    float sm = a + c, df = a - c, adf = fabsf(df), tb = b + b, ab = fabsf(tb);
    float acmx, acmn;
    if (fabsf(a) > fabsf(c)) { acmx = a; acmn = c; } else { acmx = c; acmn = a; }
    float rt;
    if (adf > ab) { float t = ab / adf; rt = adf * sqrtf(1.0f + t * t); }
    else if (adf < ab) { float t = adf / ab; rt = ab * sqrtf(1.0f + t * t); }
    else rt = ab * sqrtf(2.0f);
    int sgn1;
    if (sm < 0.0f) { rt1 = 0.5f * (sm - rt); sgn1 = -1; rt2 = (acmx / rt1) * acmn - (b / rt1) * b; }
    else if (sm > 0.0f) { rt1 = 0.5f * (sm + rt); sgn1 = 1; rt2 = (acmx / rt1) * acmn - (b / rt1) * b; }
    else { rt1 = 0.5f * rt; rt2 = -0.5f * rt; sgn1 = 1; }
    float cs; int sgn2;
    if (df >= 0.0f) { cs = df + rt; sgn2 = 1; } else { cs = df - rt; sgn2 = -1; }
    float acs = fabsf(cs);
    if (acs > ab) { float ct = -tb / cs; sn1 = 1.0f / sqrtf(1.0f + ct * ct); cs1 = ct * sn1; }
    else {
        if (ab == 0.0f) { cs1 = 1.0f; sn1 = 0.0f; }
        else { float tn = -cs / tb; cs1 = 1.0f / sqrtf(1.0f + tn * tn); sn1 = tn * cs1; }
    }
    if (sgn1 == sgn2) { float tn = cs1; cs1 = -sn1; sn1 = tn; }
}

// SSTEQR('I', n=3), f32-faithful.
__device__ void ssteqr3(float *d, float *e, float z[3][3]) {
    const int n = 3;
    const float eps = 5.9604644775390625e-08f;
    const float eps2 = eps * eps;
    const float safmin = 1.1754943508222875e-38f;
    for (int i = 0; i < 3; ++i)
        for (int j = 0; j < 3; ++j)
            z[i][j] = (i == j) ? 1.0f : 0.0f;
    const int nmaxit = n * 30;
    int jtot = 0;
    int l1 = 1;
    int l, m, lend;
    float p, g, r, c, s, f, b, rt1, rt2;
    float wc[2], wsn[2];

L10:
    if (l1 > n) goto L160;
    if (l1 > 1) e[l1 - 2] = 0.0f;
    if (l1 <= n - 1) {
        for (m = l1; m <= n - 1; ++m) {
            float tst = fabsf(e[m - 1]);
            if (tst == 0.0f) goto L30;
            if (tst <= (sqrtf(fabsf(d[m - 1])) * sqrtf(fabsf(d[m]))) * eps) {
                e[m - 1] = 0.0f;
                goto L30;
            }
        }
    }
    m = n;
L30:
    l = l1;
    lend = m;
    l1 = m + 1;
    if (lend == l) goto L10;
    {
        float anorm = 0.0f;
        for (int i = l; i <= lend; ++i) anorm = fmaxf(anorm, fabsf(d[i - 1]));
        for (int i = l; i <= lend - 1; ++i) anorm = fmaxf(anorm, fabsf(e[i - 1]));
        if (anorm == 0.0f) goto L10;
    }
    if (fabsf(d[lend - 1]) < fabsf(d[l - 1])) { int t = lend; lend = l; l = t; }

    if (lend > l) {
L40:
        if (l != lend) {
            bool found = false;
            for (m = l; m <= lend - 1; ++m) {
                float tst = e[m - 1] * e[m - 1];
                if (tst <= (eps2 * fabsf(d[m - 1])) * fabsf(d[m]) + safmin) { found = true; break; }
            }
            if (!found) m = lend;
        } else m = lend;
        if (m < lend) e[m - 1] = 0.0f;
        p = d[l - 1];
        if (m == l) goto L80;
        if (m == l + 1) {
            slaev2(d[l - 1], e[l - 1], d[l], rt1, rt2, c, s);
            for (int i = 0; i < n; ++i) {
                float tmp = z[i][l];
                z[i][l]     = c * tmp - s * z[i][l - 1];
                z[i][l - 1] = s * tmp + c * z[i][l - 1];
            }
            d[l - 1] = rt1; d[l] = rt2; e[l - 1] = 0.0f;
            l += 2;
            if (l <= lend) goto L40;
            goto L140;
        }
        if (jtot == nmaxit) goto L140;
        ++jtot;
        g = (d[l] - p) / (2.0f * e[l - 1]);
        r = slapy2(g, 1.0f);
        g = (d[m - 1] - p) + e[l - 1] / (g + f_sign(r, g));
        s = 1.0f; c = 1.0f; p = 0.0f;
        for (int i = m - 1; i >= l; --i) {
            f = s * e[i - 1];
            b = c * e[i - 1];
            slartg(g, f, c, s, r);
            if (i != m - 1) e[i] = r;
            g = d[i] - p;
            r = (d[i - 1] - g) * s + (2.0f * c) * b;
            p = s * r;
            d[i] = g + p;
            g = c * r - b;
            wc[i - 1] = c;
            wsn[i - 1] = -s;
        }
        for (int jj = m - 1; jj >= l; --jj) {
            float ct = wc[jj - 1], st = wsn[jj - 1];
            for (int i = 0; i < n; ++i) {
                float tmp = z[i][jj];
                z[i][jj]     = ct * tmp - st * z[i][jj - 1];
                z[i][jj - 1] = st * tmp + ct * z[i][jj - 1];
            }
        }
        d[l - 1] -= p;
        e[l - 1] = g;
        goto L40;
L80:
        d[l - 1] = p;
        ++l;
        if (l <= lend) goto L40;
        goto L140;
    } else {
L90:
        if (l != lend) {
            bool found = false;
            for (m = l; m >= lend + 1; --m) {
                float tst = e[m - 2] * e[m - 2];
                if (tst <= (eps2 * fabsf(d[m - 1])) * fabsf(d[m - 2]) + safmin) { found = true; break; }
            }
            if (!found) m = lend;
        } else m = lend;
        if (m > lend) e[m - 2] = 0.0f;
        p = d[l - 1];
        if (m == l) goto L130;
        if (m == l - 1) {
            slaev2(d[l - 2], e[l - 2], d[l - 1], rt1, rt2, c, s);
            for (int i = 0; i < n; ++i) {
                float tmp = z[i][l - 1];
                z[i][l - 1] = c * tmp - s * z[i][l - 2];
                z[i][l - 2] = s * tmp + c * z[i][l - 2];
            }
            d[l - 2] = rt1; d[l - 1] = rt2; e[l - 2] = 0.0f;
            l -= 2;
            if (l >= lend) goto L90;
            goto L140;
        }
        if (jtot == nmaxit) goto L140;
        ++jtot;
        g = (d[l - 2] - p) / (2.0f * e[l - 2]);
        r = slapy2(g, 1.0f);
        g = (d[m - 1] - p) + e[l - 2] / (g + f_sign(r, g));
        s = 1.0f; c = 1.0f; p = 0.0f;
        for (int i = m; i <= l - 1; ++i) {
            f = s * e[i - 1];
            b = c * e[i - 1];
            slartg(g, f, c, s, r);
            if (i != m) e[i - 2] = r;
            g = d[i - 1] - p;
            r = (d[i] - g) * s + (2.0f * c) * b;
            p = s * r;
            d[i - 1] = g + p;
            g = c * r - b;
            wc[i - 1] = c;
            wsn[i - 1] = s;
        }
        for (int jj = m; jj <= l - 1; ++jj) {
            float ct = wc[jj - 1], st = wsn[jj - 1];
            for (int i = 0; i < n; ++i) {
                float tmp = z[i][jj];
                z[i][jj]     = ct * tmp - st * z[i][jj - 1];
                z[i][jj - 1] = st * tmp + ct * z[i][jj - 1];
            }
        }
        d[l - 1] -= p;
        e[l - 2] = g;
        goto L90;
L130:
        d[l - 1] = p;
        --l;
        if (l >= lend) goto L90;
        goto L140;
    }
L140:
    if (jtot < nmaxit) goto L10;
L160:
    for (int ii = 2; ii <= n; ++ii) {
        int i = ii - 1, kk = i;
        float pp = d[i - 1];
        for (int j = ii; j <= n; ++j)
            if (d[j - 1] < pp) { kk = j; pp = d[j - 1]; }
        if (kk != i) {
            d[kk - 1] = d[i - 1];
            d[i - 1] = pp;
            for (int row = 0; row < n; ++row) {
                float t2 = z[row][i - 1];
                z[row][i - 1] = z[row][kk - 1];
                z[row][kk - 1] = t2;
            }
        }
    }
}

__device__ void ssyevd3(float a11, float a21, float a31,
                        float a22, float a32, float a33, float V[3][3]) {
    float tau1, v2, e1;
    float alpha = a21;
    float xnorm = fabsf(a31);
    if (xnorm == 0.0f) {
        tau1 = 0.0f; v2 = 0.0f; e1 = a21;
    } else {
        float beta = -f_sign(slapy2(alpha, xnorm), alpha);
        tau1 = (beta - alpha) / beta;
        float t = 1.0f / (alpha - beta);
        v2 = a31 * t;
        e1 = beta;
        float w1 = tau1 * a22;
        float w2 = tau1 * a32;
        float temp2 = a32 * v2;
        w1 = w1 + tau1 * temp2;
        float temp1 = tau1 * v2;
        w2 = w2 + temp1 * a33;
        float dot = w1;
        dot = dot + w2 * v2;
        float alpha2 = (-0.5f * tau1) * dot;
        w1 = w1 + alpha2;
        w2 = w2 + alpha2 * v2;
        a22 = (a22 - w1) - w1;
        a32 = (a32 - v2 * w1) - w2;
        a33 = (a33 - v2 * w2) - w2 * v2;
    }
    float d[3] = { a11, a22, a33 };
    float e[2] = { e1, a32 };
    float z[3][3];
    ssteqr3(d, e, z);
    for (int j = 0; j < 3; ++j) {
        float wj = z[1][j];
        wj = wj + z[2][j] * v2;
        float temp = (-tau1) * wj;
        V[0][j] = z[0][j];
        V[1][j] = z[1][j] + temp;
        V[2][j] = z[2][j] + v2 * temp;
    }
}

// Per-query geometry: r, scale, cov, ssyevd, rotate. Runs on one thread.
__device__ void geom_body(const float *__restrict__ posf, const int *__restrict__ ord,
                          int q, int k, float *__restrict__ rrot) {
    float qx = posf[3 * q], qy = posf[3 * q + 1], qz = posf[3 * q + 2];
    float rx[16], ry[16], rz[16], nrm[16];
    for (int j = 0; j < k; ++j) {
        int s = ord[j];
        rx[j] = posf[3 * s] - qx;
        ry[j] = posf[3 * s + 1] - qy;
        rz[j] = posf[3 * s + 2] - qz;
        float t = rx[j] * rx[j];
        t = t + ry[j] * ry[j];
        t = t + rz[j] * rz[j];
        nrm[j] = sqrtf(t);
    }
    float scale = nrm[0];
    for (int j = 1; j < k; ++j) scale = fmaxf(scale, nrm[j]);
    float sc = scale + 1e-8f;
    for (int j = 0; j < k; ++j) {
        rx[j] = rx[j] / sc;
        ry[j] = ry[j] / sc;
        rz[j] = rz[j] / sc;
    }
    float c00 = 0.f, c01 = 0.f, c02 = 0.f, c11 = 0.f, c12 = 0.f, c22 = 0.f;
    for (int j = 0; j < k; ++j) {
        c00 = c00 + rx[j] * rx[j];
        c01 = c01 + rx[j] * ry[j];
        c02 = c02 + rx[j] * rz[j];
        c11 = c11 + ry[j] * ry[j];
        c12 = c12 + ry[j] * rz[j];
        c22 = c22 + rz[j] * rz[j];
    }
    float fk = (float)k;
    c00 = c00 / fk; c01 = c01 / fk; c02 = c02 / fk;
    c11 = c11 / fk; c12 = c12 / fk; c22 = c22 / fk;
    float V[3][3];
    ssyevd3(c00, c01, c02, c11, c12, c22, V);
    for (int j = 0; j < k; ++j) {
        for (int col = 0; col < 3; ++col) {
            float a = rx[j] * V[0][col];
            a = a + ry[j] * V[1][col];
            a = a + rz[j] * V[2][col];
            rrot[q * 48 + j * 3 + col] = a;
        }
    }
}

// Standalone geometry: one THREAD per query (64 eigensolves per wave).
__global__ __launch_bounds__(256) void geom_kernel(
    const float *__restrict__ posf, const int *__restrict__ idx,
    int Q, int k, float *__restrict__ rrot) {
    int q = blockIdx.x * 256 + threadIdx.x;
    if (q >= Q) return;
    geom_body(posf, idx + (size_t)q * k, q, k, rrot);
}

// ---------------------------------------------------------------------------

// Also zeroes the B3-tail dot-product scalar (stream start; nothing else
// touches the last 8B of the tbuf region -- see workspace notes).
__global__ void prep_kernel(const float *__restrict__ posf, float4 *__restrict__ pos4,
                            double *__restrict__ zscalar) {
    int i = blockIdx.x * 256 + threadIdx.x;
    if (i == 0) *zscalar = 0.0;
    if (i >= 32768) return;
    float x = posf[3 * i], y = posf[3 * i + 1], z = posf[3 * i + 2];
    float t = x * x;
    t = t + y * y;
    t = t + z * z;
    pos4[i] = make_float4(x, y, z, t);
}

// Sorted-top-16 insert (lanes 0..15 hold the list ascending by (dist,idx)).
// No LDS-pipe ops: extracted candidate + kth via v_readlane (wave-uniform),
// list shift via DPP row_shr:1 (list lives entirely in row 0, lanes 0-15).
// Candidates arrive in increasing j within a wave, d==kth excluded,
// insert-after-equal -> identical semantics to reference lex top-16.
__device__ __forceinline__ void insert16(float d, int jbase, int lane,
                                         float &ld, int &li, float &kth) {
    unsigned long long mask = __ballot(d < kth);
    while (mask) {
        int src = __ffsll(mask) - 1;
        mask &= mask - 1;
        float dv = __int_as_float(__builtin_amdgcn_readlane(__float_as_int(d), src));
        int jv = jbase + src;
        if (dv < kth) {
            unsigned long long lm = __ballot((lane < 16) && (ld <= dv));
            int p2 = __popcll(lm);
            float sd = __int_as_float(__builtin_amdgcn_update_dpp(
                0, __float_as_int(ld), 0x111, 0xf, 0xf, true));
            int si = __builtin_amdgcn_update_dpp(0, li, 0x111, 0xf, 0xf, true);
            if (lane < 16) {
                if (lane == p2) { ld = dv; li = jv; }
                else if (lane > p2) { ld = sd; li = si; }
            }
            kth = __int_as_float(__builtin_amdgcn_readlane(__float_as_int(ld), 15));
        }
    }
}

// Init the top-16 list from 64 candidates via full 64-lane bitonic sort on
// lex key (dist, idx) ascending. Equivalent to sequentially inserting the 64
// distinct (d, jbase+lane) pairs into an empty list: lanes 0-15 = 16
// lex-smallest ascending; kth = lane 15. idx uniqueness -> total order.
__device__ __forceinline__ void sort64_init(float d, int jbase, int lane,
                                            float &ld, int &li, float &kth) {
    float v = d;
    int vi = jbase + lane;
#pragma unroll
    for (int k2 = 2; k2 <= 64; k2 <<= 1) {
#pragma unroll
        for (int j2 = k2 >> 1; j2 > 0; j2 >>= 1) {
            float ov = __shfl_xor(v, j2);
            int oi = __shfl_xor(vi, j2);
            bool oless = (ov < v) || (ov == v && oi < vi);
            bool dir = ((lane & k2) == 0);        // ascending block?
            bool keepmin = (((lane & j2) == 0) == dir);
            bool take = keepmin ? oless : !oless;
            if (take) { v = ov; vi = oi; }
        }
    }
    if (lane < 16) { ld = v; li = vi; }
    kth = __int_as_float(__builtin_amdgcn_readlane(__float_as_int(v), 15));
}

// Wave-level scan of candidate range [start,end) with prefetch + sort-init +
// pre-ballot tile skip. Returns per-wave sorted top-16 in (ld, li) lanes 0-15.
__device__ __forceinline__ void scan_range(
    const float4 *__restrict__ pos4, float4 qp, int start, int end, int lane,
    float &ld, int &li, float &kth) {
    const float FINF = 3.0e38f;
    int base = start;
    float4 c0, c1, c2, c3;
    bool have = (base + 256 <= end);
    bool first = true;
    if (have) {
        c0 = pos4[base + lane];
        c1 = pos4[base + 64 + lane];
        c2 = pos4[base + 128 + lane];
        c3 = pos4[base + 192 + lane];
    }
    while (have) {
        int nbase = base + 1024;
        bool nhave = (nbase + 256 <= end);
        float4 n0 = c0, n1 = c1, n2 = c2, n3 = c3;
        if (nhave) {
            n0 = pos4[nbase + lane];
            n1 = pos4[nbase + 64 + lane];
            n2 = pos4[nbase + 128 + lane];
            n3 = pos4[nbase + 192 + lane];
        }
        float m0 = fmaf(qp.x, c0.x, 0.0f);
        m0 = fmaf(qp.y, c0.y, m0);
        m0 = fmaf(qp.z, c0.z, m0);
        float d0 = (qp.w + c0.w) - 2.0f * m0;   // bit-identical reference sgemm form
        float m1 = fmaf(qp.x, c1.x, 0.0f);
        m1 = fmaf(qp.y, c1.y, m1);
        m1 = fmaf(qp.z, c1.z, m1);
        float d1 = (qp.w + c1.w) - 2.0f * m1;
        float m2 = fmaf(qp.x, c2.x, 0.0f);
        m2 = fmaf(qp.y, c2.y, m2);
        m2 = fmaf(qp.z, c2.z, m2);
        float d2 = (qp.w + c2.w) - 2.0f * m2;
        float m3 = fmaf(qp.x, c3.x, 0.0f);
        m3 = fmaf(qp.y, c3.y, m3);
        m3 = fmaf(qp.z, c3.z, m3);
        float d3 = (qp.w + c3.w) - 2.0f * m3;
        // Pre-ballot tile skip: kth only tightens, so if no lane's min
        // passes now, none of the 4 sub-tiles can insert. Semantics equal.
        float dmin = fminf(fminf(d0, d1), fminf(d2, d3));
        if (first || __ballot(dmin < kth)) {
            if (first) {
                sort64_init(d0, base, lane, ld, li, kth);
                first = false;
            } else {
                insert16(d0, base, lane, ld, li, kth);
            }
            insert16(d1, base + 64, lane, ld, li, kth);
            insert16(d2, base + 128, lane, ld, li, kth);
            insert16(d3, base + 192, lane, ld, li, kth);
        }
        c0 = n0; c1 = n1; c2 = n2; c3 = n3;
        base = nbase;
        have = nhave;
    }
    if (base < end) {
#pragma unroll
        for (int k2 = 0; k2 < 4; ++k2) {
            int j = base + k2 * 64 + lane;
            float dd = FINF;
            if (j < end) {
                float4 p = pos4[j];
                float m = fmaf(qp.x, p.x, 0.0f);
                m = fmaf(qp.y, p.y, m);
                m = fmaf(qp.z, p.z, m);
                dd = (qp.w + p.w) - 2.0f * m;
            }
            insert16(dd, base + k2 * 64, lane, ld, li, kth);
        }
    }
}

// Two-stage bitonic merge of four sorted 16-lists (md/mi[64]) -> sorted 16
// in lanes 0-15 (v2, vi2). Lex key (dist,idx) ascending. r1-verified.
__device__ __forceinline__ void merge4x16(const float *md, const int *mi,
                                          int lane, float &v2, int &vi2) {
    int l16 = lane & 15;
    int srcA = (lane >> 5) * 32 + ((lane & 16) ? (16 + (15 - l16)) : l16);
    float v = md[srcA];
    int vi = mi[srcA];
    for (int off = 16; off > 0; off >>= 1) {
        float ov = __shfl_xor(v, off);
        int oi = __shfl_xor(vi, off);
        bool oless = (ov < v) || (ov == v && oi < vi);
        bool take = (lane & off) ? (!oless) : oless;
        if (take) { v = ov; vi = oi; }
    }
    int src2 = (lane < 16) ? lane : (63 - lane);
    v2 = __shfl(v, src2);
    vi2 = __shfl(vi, src2);
    for (int off = 16; off > 0; off >>= 1) {
        float ov = __shfl_xor(v2, off);
        int oi = __shfl_xor(vi2, off);
        bool oless = (ov < v2) || (ov == v2 && oi < vi2);
        bool take = (lane & off) ? (!oless) : oless;
        if (take) { v2 = ov; vi2 = oi; }
    }
}

// k=16 kNN. 1 query/block, 4 waves, 4 candidates/lane/iter; wave w scans
// base=w*256 stride 1024 -- identical candidate partition/order to the
// verified r5 kernel. DOGEOM=1 instantiation (small Q) runs the lane-0
// geometry tail in-block; DOGEOM=0 (hot large-Q path) stays lean (VGPR 28).
template <int DOGEOM>
__global__ __launch_bounds__(256) void knng16_kernel(
    const float4 *__restrict__ pos4, const float *__restrict__ posf,
    int S, int *__restrict__ idx_out, float *__restrict__ rrot) {
    __shared__ float md[64];
    __shared__ int mi[64];
    __shared__ int ord[16];
    int q = blockIdx.x;
    int tid = threadIdx.x;
    int lane = tid & 63;
    int w = tid >> 6;
    float4 qp = pos4[q];
    const float FINF = 3.0e38f;
    float ld = FINF;
    int li = 0x7fffffff;
    float kth = FINF;
    scan_range(pos4, qp, w * 256, S, lane, ld, li, kth);
    if (lane < 16) { md[w * 16 + lane] = ld; mi[w * 16 + lane] = li; }
    __syncthreads();
    if (w == 0) {
        float v2; int vi2;
        merge4x16(md, mi, lane, v2, vi2);
        if (lane < 16) {
            idx_out[q * 16 + lane] = vi2;
            if (DOGEOM) ord[lane] = vi2;
        }
        if (DOGEOM && lane == 0) geom_body(posf, ord, q, 16, rrot);
    }
}

// Small-S (S <= 64) kNN + in-block geometry; one wave per query (small Q).
__global__ __launch_bounds__(64) void knngs_kernel(
    const float4 *__restrict__ pos4, const float *__restrict__ posf,
    int S, int k, int *__restrict__ idx_out, float *__restrict__ rrot) {
    __shared__ int ord[16];
    int q = blockIdx.x;
    int lane = threadIdx.x;
    float4 qp = pos4[q];
    const float FINF = 3.0e38f;
    float dist = FINF;
    if (lane < S) {
        float4 p = pos4[lane];
        float m = fmaf(qp.x, p.x, 0.0f);
        m = fmaf(qp.y, p.y, m);
        m = fmaf(qp.z, p.z, m);
        dist = (qp.w + p.w) - 2.0f * m;
    }
    bool used = false;
    for (int r = 0; r < k; ++r) {
        float v = used ? FINF : dist;
        int vid = (used || lane >= S) ? 0x7fffffff : lane;
        for (int off = 32; off > 0; off >>= 1) {
            float ov = __shfl_down(v, off);
            int oid = __shfl_down(vid, off);
            if (ov < v || (ov == v && oid < vid)) { v = ov; vid = oid; }
        }
        vid = __shfl(vid, 0);
        if (lane == 0) { idx_out[q * k + r] = vid; ord[r] = vid; }
        if (lane == vid) used = true;
    }
    if (lane == 0) geom_body(posf, ord, q, k, rrot);
}

__device__ __forceinline__ void compute_phi(const float *rrot, int q, int tid,
                                            double phi[45]) {
    double x = (double)rrot[q * 48 + tid * 3 + 0];
    double y = (double)rrot[q * 48 + tid * 3 + 1];
    double z = (double)rrot[q * 48 + tid * 3 + 2];
    double px[5], py[3], pz[3];
    px[0] = 1.0; px[1] = x; px[2] = x * x; px[3] = px[2] * x; px[4] = px[3] * x;
    py[0] = 1.0; py[1] = y; py[2] = y * y;
    pz[0] = 1.0; pz[1] = z; pz[2] = z * z;
#pragma unroll
    for (int n2 = 0; n2 < 5; ++n2)
#pragma unroll
        for (int l2 = 0; l2 < 3; ++l2)
#pragma unroll
            for (int m2 = 0; m2 < 3; ++m2)
                phi[n2 * 9 + l2 * 3 + m2] = (px[n2] * py[l2]) * pz[m2];
}

// Generic per-query fused conv (B0-L1, C=4).
__global__ __launch_bounds__(256) void feat_kernel(
    const float *__restrict__ rrot, const int *__restrict__ idx, int k,
    const double *__restrict__ fin64, const float *__restrict__ fin32, int C,
    const float *__restrict__ W, const float *__restrict__ bias, int O,
    double *__restrict__ fout) {
    __shared__ double phi_sh[16][45];
    __shared__ int idx_sh[16];
    __shared__ double red_sh[256];
    extern __shared__ double dyn[];
    double *nf = dyn;            // [16][C]
    double *t = dyn + 16 * C;    // [9][C]
    int q = blockIdx.x;
    int tid = threadIdx.x;
    int OT = O < 256 ? O : 256;
    int nseg = 256 / OT;
    int o = tid % OT;
    int seg = tid / OT;
    int cseg = C / nseg;
    int c0 = seg * cseg, c1 = c0 + cseg;
    if (tid < k) {
        idx_sh[tid] = idx[q * k + tid];
        double phi[45];
        compute_phi(rrot, q, tid, phi);
#pragma unroll
        for (int b2 = 0; b2 < 45; ++b2) phi_sh[tid][b2] = phi[b2];
    }
    __syncthreads();
    for (int e2 = tid; e2 < k * C; e2 += 256) {
        int j = e2 / C, cc = e2 - j * C;
        size_t src = (size_t)idx_sh[j] * C + cc;
        nf[j * C + cc] = fin32 ? (double)fin32[src] : fin64[src];
    }
    __syncthreads();
    double accp = 0.0;
    for (int ch = 0; ch < 45; ch += 9) {
        for (int e2 = tid; e2 < 9 * C; e2 += 256) {
            int b2 = e2 / C, cc = e2 - b2 * C;
            double a2 = 0.0;
            for (int j = 0; j < k; ++j) a2 = fma(phi_sh[j][ch + b2], nf[j * C + cc], a2);
            t[e2] = a2 / (double)k;
        }
        __syncthreads();
        double a0 = 0.0, a1 = 0.0;
        for (int b2 = 0; b2 < 9; ++b2) {
            const float *wp = W + (size_t)(ch + b2) * C * O + o;
            const double *tp = t + b2 * C;
            int cc = c0;
            for (; cc + 2 <= c1; cc += 2) {
                a0 = fma(tp[cc],     (double)wp[(size_t)cc * O], a0);
                a1 = fma(tp[cc + 1], (double)wp[(size_t)(cc + 1) * O], a1);
            }
            for (; cc < c1; ++cc) a0 = fma(tp[cc], (double)wp[(size_t)cc * O], a0);
        }
        accp += a0 + a1;
        __syncthreads();
    }
    red_sh[tid] = accp;
    __syncthreads();
    if (tid < OT) {
        double v = 0.0;
        for (int s2 = 0; s2 < nseg; ++s2) v += red_sh[tid + s2 * OT];
        v += (double)bias[tid];
        fout[(size_t)q * O + tid] = v > 0.0 ? v : 0.0;
    }
}

// Specialized C=64, O=64, k=16 fused conv (B0-L2), 2 queries per block.
__global__ __launch_bounds__(256) void feat64_kernel(
    const float *__restrict__ rrot, const int *__restrict__ idx,
    const double *__restrict__ fin, const float *__restrict__ W,
    const float *__restrict__ bias, int Q, double *__restrict__ fout) {
    __shared__ double phi_sh[2][16][45];
    __shared__ int idx_sh[2][16];
    __shared__ double nf[2][16][64];
    __shared__ double t[2][9][64];
    __shared__ double red[16][64];
    int q0 = blockIdx.x * 2;
    int nq = (Q - q0) < 2 ? (Q - q0) : 2;
    int tid = threadIdx.x;
    int tx = tid & 15;
    int seg = tid >> 4;
    int o0 = tx * 4;
    int cbase = seg * 4;
    if (tid < 32) {
        int qi = tid >> 4, j = tid & 15;
        int qq = q0 + (qi < nq ? qi : 0);
        idx_sh[qi][j] = idx[qq * 16 + j];
        double phi[45];
        compute_phi(rrot, qq, j, phi);
#pragma unroll
        for (int b2 = 0; b2 < 45; ++b2) phi_sh[qi][j][b2] = phi[b2];
    }
    __syncthreads();
    for (int e2 = tid; e2 < 2 * 16 * 64; e2 += 256) {
        int qi = e2 >> 10, j = (e2 >> 6) & 15, cc = e2 & 63;
        nf[qi][j][cc] = fin[(size_t)idx_sh[qi][j] * 64 + cc];
    }
    __syncthreads();
    double acc[2][4] = {{0.0, 0.0, 0.0, 0.0}, {0.0, 0.0, 0.0, 0.0}};
    for (int ch = 0; ch < 45; ch += 9) {
        for (int e2 = tid; e2 < 2 * 9 * 64; e2 += 256) {
            int qi = e2 / 576, rem = e2 - qi * 576;
            int b2 = rem >> 6, cc = rem & 63;
            double a2 = 0.0;
#pragma unroll
            for (int j = 0; j < 16; ++j) a2 = fma(phi_sh[qi][j][ch + b2], nf[qi][j][cc], a2);
            t[qi][b2][cc] = a2 * 0.0625;
        }
        __syncthreads();
#pragma unroll
        for (int b2 = 0; b2 < 9; ++b2) {
            const float *wrow = W + ((size_t)(ch + b2) * 64 + cbase) * 64 + o0;
#pragma unroll
            for (int i = 0; i < 4; ++i) {
                float4 wv = *(const float4 *)(wrow + (size_t)i * 64);
                double w0 = (double)wv.x, w1 = (double)wv.y;
                double w2 = (double)wv.z, w3 = (double)wv.w;
                double tv0 = t[0][b2][cbase + i];
                double tv1 = t[1][b2][cbase + i];
                acc[0][0] = fma(tv0, w0, acc[0][0]);
                acc[0][1] = fma(tv0, w1, acc[0][1]);
                acc[0][2] = fma(tv0, w2, acc[0][2]);
                acc[0][3] = fma(tv0, w3, acc[0][3]);
                acc[1][0] = fma(tv1, w0, acc[1][0]);
                acc[1][1] = fma(tv1, w1, acc[1][1]);
                acc[1][2] = fma(tv1, w2, acc[1][2]);
                acc[1][3] = fma(tv1, w3, acc[1][3]);
            }
        }
        __syncthreads();
    }
    for (int qi = 0; qi < nq; ++qi) {
        red[seg][o0 + 0] = acc[qi][0];
        red[seg][o0 + 1] = acc[qi][1];
        red[seg][o0 + 2] = acc[qi][2];
        red[seg][o0 + 3] = acc[qi][3];
        __syncthreads();
        if (tid < 64) {
            double v = 0.0;
#pragma unroll
            for (int s2 = 0; s2 < 16; ++s2) v += red[s2][tid];
            v += (double)bias[tid];
            fout[(size_t)(q0 + qi) * 64 + tid] = v > 0.0 ? v : 0.0;
        }
        __syncthreads();
    }
}

// Stage 1 (small Q): t[q-q0][45*C], grid (qcount, 5 basis chunks of 9).
// blockIdx.y==0 blocks also zero this q's fout row (replaces hipMemsetAsync;
// gemm's atomics run in a strictly later kernel, so no race).
// fbias != nullptr: fin holds the previous gemm's RAW accumulator; apply
// v = relu(fin + bias) on read -- identical f64 op order to a finalize pass.
__global__ __launch_bounds__(256) void t_kernel(
    const float *__restrict__ rrot, const int *__restrict__ idx, int k,
    const double *__restrict__ fin, const float *__restrict__ fbias, int C,
    int q0, double *__restrict__ tbuf, double *__restrict__ fout, int O) {
    __shared__ double phi_sh[16][45];
    __shared__ int idx_sh[16];
    extern __shared__ double nf[];  // [16][C]
    int q = q0 + blockIdx.x;
    int bch = blockIdx.y * 9;
    int tid = threadIdx.x;
    if (blockIdx.y == 0) {
        for (int i = tid; i < O; i += 256) fout[(size_t)q * O + i] = 0.0;
    }
    if (tid < k) {
        idx_sh[tid] = idx[q * k + tid];
        double phi[45];
        compute_phi(rrot, q, tid, phi);
#pragma unroll
        for (int b2 = 0; b2 < 45; ++b2) phi_sh[tid][b2] = phi[b2];
    }
    __syncthreads();
    for (int e2 = tid; e2 < k * C; e2 += 256) {
        int j = e2 / C, cc = e2 - j * C;
        double v = fin[(size_t)idx_sh[j] * C + cc];
        if (fbias) {
            v = v + (double)fbias[cc];
            v = v > 0.0 ? v : 0.0;
        }
        nf[j * C + cc] = v;
    }
    __syncthreads();
    int K = 45 * C;
    for (int e2 = tid; e2 < 9 * C; e2 += 256) {
        int b2 = bch + e2 / C, cc = e2 % C;
        double a2 = 0.0;
        for (int j = 0; j < k; ++j) a2 = fma(phi_sh[j][b2], nf[j * C + cc], a2);
        tbuf[(size_t)blockIdx.x * K + b2 * C + cc] = a2 / (double)k;
    }
}

// Stage 2: K-split GEMM, f64 atomics straight into acc (= fout region).
// Unroll-8, 8 independent accumulators, double2 tp loads (tbuf 16B-aligned,
// kchunk forced to a multiple of 8 by the launcher).
__global__ __launch_bounds__(256) void gemm_kernel(
    const double *__restrict__ tbuf, const float *__restrict__ W,
    int K, int O, int q0, int q1, int kchunk, double *__restrict__ acc) {
    int OT = O < 256 ? O : 256;
    int qpb = 256 / OT;
    int tid = threadIdx.x;
    int o = blockIdx.x * OT + (tid % OT);
    int q = q0 + blockIdx.y * qpb + tid / OT;
    if (q >= q1) return;
    int k0 = blockIdx.z * kchunk;
    if (k0 >= K) return;
    int kend = min(k0 + kchunk, K);
    const double *tp = tbuf + (size_t)(q - q0) * K;
    const float *wp = W + (size_t)k0 * O + o;
    double a0 = 0.0, a1 = 0.0, a2 = 0.0, a3 = 0.0;
    double a4 = 0.0, a5 = 0.0, a6 = 0.0, a7 = 0.0;
    int kk = k0;
    for (; kk + 8 <= kend; kk += 8) {
        double2 t01 = *(const double2 *)(tp + kk);
        double2 t23 = *(const double2 *)(tp + kk + 2);
        double2 t45 = *(const double2 *)(tp + kk + 4);
        double2 t67 = *(const double2 *)(tp + kk + 6);
        float w0 = wp[0];
        float w1 = wp[(size_t)O];
        float w2 = wp[2 * (size_t)O];
        float w3 = wp[3 * (size_t)O];
        float w4 = wp[4 * (size_t)O];
        float w5 = wp[5 * (size_t)O];
        float w6 = wp[6 * (size_t)O];
        float w7 = wp[7 * (size_t)O];
        a0 = fma(t01.x, (double)w0, a0);
        a1 = fma(t01.y, (double)w1, a1);
        a2 = fma(t23.x, (double)w2, a2);
        a3 = fma(t23.y, (double)w3, a3);
        a4 = fma(t45.x, (double)w4, a4);
        a5 = fma(t45.y, (double)w5, a5);
        a6 = fma(t67.x, (double)w6, a6);
        a7 = fma(t67.y, (double)w7, a7);
        wp += 8 * (size_t)O;
    }
    for (; kk < kend; ++kk) {
        a0 = fma(tp[kk], (double)wp[0], a0);
        wp += (size_t)O;
    }
    double s = ((a0 + a1) + (a2 + a3)) + ((a4 + a5) + (a6 + a7));
    atomicAdd(&acc[(size_t)q * O + o], s);
}

__global__ void resid0_kernel(const float *__restrict__ chanf, const float *__restrict__ p,
                              const double *__restrict__ x, double *__restrict__ fout) {
    int i = blockIdx.x * 256 + threadIdx.x;
    if (i >= 2435 * 64) return;
    int q = i >> 6, o = i & 63;
    const float *f = chanf + 4 * q;
    float c = fmaf(f[0], p[o], 0.0f);
    c = fmaf(f[1], p[64 + o], c);
    c = fmaf(f[2], p[128 + o], c);
    c = fmaf(f[3], p[192 + o], c);
    double v = x[i] + (double)c;
    fout[i] = v > 0.0 ? v : 0.0;
}

// Fused finalize + residual: x = relu(acc + bias); fout = relu(x + fin@p).
// Identical op order to finalize followed by the residual pass.
__global__ void resid64f_kernel(const float *__restrict__ bias,
                                const double *__restrict__ acc,
                                const double *__restrict__ fin, int Cin,
                                const float *__restrict__ p,
                                int Q, int Cout, double *__restrict__ fout) {
    int i = blockIdx.x * blockDim.x + threadIdx.x;
    if (i >= Q * Cout) return;
    int q = i / Cout, o = i - q * Cout;
    double v = acc[i] + (double)bias[o];
    double x = v > 0.0 ? v : 0.0;
    double a = 0.0;
    for (int c = 0; c < Cin; ++c) a = fma(fin[q * Cin + c], (double)p[c * Cout + o], a);
    double r = x + a;
    fout[i] = r > 0.0 ? r : 0.0;
}

// B3 tail stage A (parallel across 8 blocks / 8 CUs): block b owns outputs
// i in [64b, 64b+64); 4 threads per output each sum 64 of the 256 c-terms
// (coalesced p reads); LDS reduce -> r_i = relu(relu(acc+bias)+dot); block
// reduces sum(r_i * hw_i) and atomicAdds into the f64 scalar (zeroed by
// prep_kernel). f64 reassociation within the feature-path slack.
__global__ __launch_bounds__(256) void rvdot_kernel(
    const float *__restrict__ bias, const double *__restrict__ acc,
    const double *__restrict__ fin, int Cin, const float *__restrict__ p,
    const float *__restrict__ hw, double *__restrict__ scalar) {
    __shared__ double part[256];
    __shared__ double rvs[64];
    int tid = threadIdx.x;
    int i = blockIdx.x * 64 + (tid >> 2);
    int cp = tid & 3;
    int clen = Cin / 4;
    int c0 = cp * clen;
    double a = 0.0;
    for (int c = c0; c < c0 + clen; ++c)
        a = fma(fin[c], (double)p[c * 512 + i], a);
    part[tid] = a;
    __syncthreads();
    if (cp == 0) {
        double dot = (part[tid] + part[tid + 1]) + (part[tid + 2] + part[tid + 3]);
        double v = acc[i] + (double)bias[i];
        double x = v > 0.0 ? v : 0.0;
        double r = x + dot;
        r = r > 0.0 ? r : 0.0;
        rvs[tid >> 2] = r * (double)hw[i];
    }
    __syncthreads();
    if (tid == 0) {
        double s = 0.0;
        for (int j = 0; j < 64; ++j) s += rvs[j];
        atomicAdd(scalar, s);
    }
}

// B3 tail stage B: out = (float)(scalar + hb). Single 8-byte read.
__global__ void outhead_kernel(const double *__restrict__ scalar,
                               const float *__restrict__ hb,
                               float *__restrict__ out) {
    if (threadIdx.x == 0 && blockIdx.x == 0)
        out[0] = (float)(*scalar + (double)hb[0]);
}

// ---------------------------------------------------------------------------

extern "C" void kernel_launch(void *const *d_in, const int *in_sizes, int n_in,
                              void *d_out, int out_size, void *d_ws, size_t ws_size,
                              hipStream_t stream) {
    (void)in_sizes; (void)n_in; (void)out_size;

    const float *posf = (const float *)d_in[0];
    const float *chanf = (const float *)d_in[1];
    const float *W[8], *B[8];
    for (int li = 1; li <= 7; ++li) {
        W[li] = (const float *)d_in[2 + 2 * (li - 1)];
        B[li] = (const float *)d_in[3 + 2 * (li - 1)];
    }
    const float *P[5];
    for (int bi = 1; bi <= 4; ++bi) P[bi] = (const float *)d_in[15 + bi];
    const float *hw = (const float *)d_in[20];
    const float *hb = (const float *)d_in[21];

    // workspace layout (bytes)
    char *wsb = (char *)d_ws;
    double *B1   = (double *)(wsb + 0);            // 2435*64 f64 = 1,246,720
    double *B2   = (double *)(wsb + 1246720);
    double *B3   = (double *)(wsb + 2493440);
    float *rrot  = (float *)(wsb + 3740160);       // 2435*48 f32 = 467,520
    int *idx     = (int *)(wsb + 4207680);         // 2435*16 = 155,840
    float4 *pos4 = (float4 *)(wsb + 4363520);      // 32768*16 = 524,288
    double *tbuf = (double *)(wsb + 4887808);      // 4 MB (small-Q chunks)
    // B3-tail dot scalar: last 8B of the tbuf region. Never written by any
    // t_kernel: B1's largest chunk writes 91*5760*8 = 4,193,280 <= 4MB-1024;
    // B2/B3 write far less. Zeroed by prep_kernel at stream start.
    double *dsc  = (double *)(wsb + 9082112 - 8);
    if (ws_size < 9082112) return;

    prep_kernel<<<128, 256, 0, stream>>>(posf, pos4, dsc);

    // Large Q: selection-only kNN + parallel geom kernel (r7 win).
    // Small Q: geometry fused in-block (launch overhead > parallel tail).
    auto knng = [&](int Q, int S, int k) {
        if (S <= 64) {
            knngs_kernel<<<Q, 64, 0, stream>>>(pos4, posf, S, k, idx, rrot);
        } else if (Q >= 512) {
            knng16_kernel<0><<<Q, 256, 0, stream>>>(pos4, posf, S, idx, rrot);
            geom_kernel<<<(Q + 255) / 256, 256, 0, stream>>>(posf, idx, Q, k, rrot);
        } else {
            knng16_kernel<1><<<Q, 256, 0, stream>>>(pos4, posf, S, idx, rrot);
        }
    };

    // fused per-query path (B0-L1)
    auto conv = [&](int Q, int S, int k, const double *fin64, const float *fin32, int C,
                    const float *w, const float *bias, int O, double *fout) {
        knng(Q, S, k);
        size_t dyn = (size_t)(16 + 9) * C * sizeof(double);
        feat_kernel<<<Q, 256, dyn, stream>>>(rrot, idx, k, fin64, fin32, C, w, bias, O, fout);
    };

    // specialized C=64/O=64 path (B0-L2)
    auto conv64 = [&](int Q, int S, const double *fin, const float *w,
                      const float *bias, double *fout) {
        knng(Q, S, 16);
        feat64_kernel<<<(Q + 1) / 2, 256, 0, stream>>>(rrot, idx, fin, w, bias, Q, fout);
    };

    // split t + K-parallel GEMM path (small Q) -- K-split grid is essential.
    // fout is left as RAW atomic acc; the layer's bias+relu is applied by
    // the consumer (next t_kernel's fbias, or resid64f/rvdot).
    auto conv2 = [&](int Q, int S, int k, const double *fin, const float *fbias,
                     int C, const float *w, int O, double *fout,
                     int ksplit, bool skip_knn) {
        if (!skip_knn) knng(Q, S, k);
        int K = 45 * C;
        int qc = 4194304 / (K * 8);
        if (qc > Q) qc = Q;
        int OT = O < 256 ? O : 256;
        int qpb = 256 / OT;
        int kchunk = (((K + ksplit - 1) / ksplit) + 7) & ~7;
        for (int q0 = 0; q0 < Q; q0 += qc) {
            int qn = min(qc, Q - q0);
            dim3 gt(qn, 5);
            t_kernel<<<gt, 256, (size_t)16 * C * sizeof(double), stream>>>(
                rrot, idx, k, fin, fbias, C, q0, tbuf, fout, O);
            dim3 g(O / OT, (qn + qpb - 1) / qpb, ksplit);
            gemm_kernel<<<g, 256, 0, stream>>>(tbuf, w, K, O, q0, q0 + qn, kchunk, fout);
        }
    };

    // Block 0 (Q=2435)
    conv(2435, 32768, 16, nullptr, chanf, 4, W[1], B[1], 64, B1);
    conv64(2435, 2435, B1, W[2], B[2], B2);
    resid0_kernel<<<(2435 * 64 + 255) / 256, 256, 0, stream>>>(chanf, P[1], B2, B3);
    // Block 1 (Q=181)
    // L3 kNN == rows 0..180 of B0-L2's knn(pos[:2435],pos[:2435]) -> skip.
    conv2(181, 2435, 16, B3, nullptr, 64, W[3], 128, B1, 48, true);
    // L4: fin = L3's raw acc -> fbias = B[3].
    conv2(181, 181, 16, B1, B[3], 128, W[4], 128, B2, 48, false);
    resid64f_kernel<<<(181 * 128 + 255) / 256, 256, 0, stream>>>(
        B[4], B2, B3, 64, P[2], 181, 128, B1);
    // Block 2 (Q=13)
    // L5 kNN == rows 0..12 of B1-L4's knn(pos[:181],pos[:181]) -> skip.
    conv2(13, 181, 16, B1, nullptr, 128, W[5], 256, B2, 160, true);
    // L6: fin = L5's raw acc -> fbias = B[5].
    conv2(13, 13, 13, B2, B[5], 256, W[6], 256, B3, 160, false);
    resid64f_kernel<<<(13 * 256 + 255) / 256, 256, 0, stream>>>(
        B[6], B3, B1, 128, P[3], 13, 256, B2);
    // Block 3 (Q=1)
    // L7 kNN == row 0 of B2-L6's knn(pos[:13],pos[:13],k=13) -> skip.
    conv2(1, 13, 13, B2, nullptr, 256, W[7], 512, B1, 320, true);
    // Parallel B3 tail: rvdot (8 blocks) + scalar head.
    rvdot_kernel<<<8, 256, 0, stream>>>(B[7], B1, B2, 256, P[4], hw, dsc);
    outhead_kernel<<<1, 64, 0, stream>>>(dsc, hb, (float *)d_out);
}

// Round 10
// 741.223 us; speedup vs baseline: 1.0746x; 1.0129x over previous
//
#include <hip/hip_runtime.h>
#include <math.h>

// Correctness-critical invariant: kNN sets and eigenvectors must stay
// bit-identical to numpy/LAPACK (f32, contract off). The f64 feature path has
// large rounding slack (absmax 0.0 at threshold 6.7e-5) -> reassociation and
// f64 atomics are safe there. W f32->f64 conversion is exact.
//
// LESSON (r8-old): small-Q layers NEED the K-split grid dimension.
// LESSON (r2/r6): partitions per query multiply tracker work ~linearly.
// LESSON (r7): serial lane-0 geometry tail hoisted out of hot kNN ->
// 125->78us, FETCH 15.6->2.2MB. Small-Q keeps fused geom.
// LESSON (r8/r9): 1-block tail kernels are ~100us latency traps; rvdot
// parallelization recovered 46us. Launch overhead is ~1-2us/launch (cuts
// were neutral), so only kernel-time targets matter.
//
// THEORY (r10): knng16 (77us, busy 66%) carries ~512 instr/wave of pure
// prefetch-copy movs (16/iter x 32) -> 2-deep ping-pong unroll removes them
// with IDENTICAL candidate order (tiles in increasing base per wave).
// rvdot widened to 16 blocks x 8 thr/output (shorter chains, 2x CU spread).
#pragma clang fp contract(off)

// ---------------------------------------------------------------------------
__device__ __forceinline__ float f_sign(float a, float b) {
    return (b >= 0.0f) ? fabsf(a) : -fabsf(a);
}

__device__ float slapy2(float x, float y) {
    float xa = fabsf(x), ya = fabsf(y);
    float w = fmaxf(xa, ya), z = fminf(xa, ya);
    if (z == 0.0f) return w;
    float t = z / w;
    return w * sqrtf(1.0f + t * t);
}

__device__ void slartg(float f, float g, float &cs, float &sn, float &r) {
    if (g == 0.0f) { cs = 1.0f; sn = 0.0f; r = f; }
    else if (f == 0.0f) { cs = 0.0f; sn = f_sign(1.0f, g); r = fabsf(g); }
    else {
        float d = sqrtf(f * f + g * g);
        float p = 1.0f / d;
        cs = fabsf(f) * p;
        sn = g * f_sign(p, f);
        r = f_sign(d, f);
    }
}

__device__ void slaev2(float a, float b, float c,
                       float &rt1, float &rt2, float &cs1, float &sn1) {
    float sm = a + c, df = a - c, adf = fabsf(df), tb = b + b, ab = fabsf(tb);
    float acmx, acmn;
    if (fabsf(a) > fabsf(c)) { acmx = a; acmn = c; } else { acmx = c; acmn = a; }
    float rt;
    if (adf > ab) { float t = ab / adf; rt = adf * sqrtf(1.0f + t * t); }
    else if (adf < ab) { float t = adf / ab; rt = ab * sqrtf(1.0f + t * t); }
    else rt = ab * sqrtf(2.0f);
    int sgn1;
    if (sm < 0.0f) { rt1 = 0.5f * (sm - rt); sgn1 = -1; rt2 = (acmx / rt1) * acmn - (b / rt1) * b; }
    else if (sm > 0.0f) { rt1 = 0.5f * (sm + rt); sgn1 = 1; rt2 = (acmx / rt1) * acmn - (b / rt1) * b; }
    else { rt1 = 0.5f * rt; rt2 = -0.5f * rt; sgn1 = 1; }
    float cs; int sgn2;
    if (df >= 0.0f) { cs = df + rt; sgn2 = 1; } else { cs = df - rt; sgn2 = -1; }
    float acs = fabsf(cs);
    if (acs > ab) { float ct = -tb / cs; sn1 = 1.0f / sqrtf(1.0f + ct * ct); cs1 = ct * sn1; }
    else {
        if (ab == 0.0f) { cs1 = 1.0f; sn1 = 0.0f; }
        else { float tn = -cs / tb; cs1 = 1.0f / sqrtf(1.0f + tn * tn); sn1 = tn * cs1; }
    }
    if (sgn1 == sgn2) { float tn = cs1; cs1 = -sn1; sn1 = tn; }
}

// SSTEQR('I', n=3), f32-faithful.
__device__ void ssteqr3(float *d, float *e, float z[3][3]) {
    const int n = 3;
    const float eps = 5.9604644775390625e-08f;
    const float eps2 = eps * eps;
    const float safmin = 1.1754943508222875e-38f;
    for (int i = 0; i < 3; ++i)
        for (int j = 0; j < 3; ++j)
            z[i][j] = (i == j) ? 1.0f : 0.0f;
    const int nmaxit = n * 30;
    int jtot = 0;
    int l1 = 1;
    int l, m, lend;
    float p, g, r, c, s, f, b, rt1, rt2;
    float wc[2], wsn[2];

L10:
    if (l1 > n) goto L160;
    if (l1 > 1) e[l1 - 2] = 0.0f;
    if (l1 <= n - 1) {
        for (m = l1; m <= n - 1; ++m) {
            float tst = fabsf(e[m - 1]);
            if (tst == 0.0f) goto L30;
            if (tst <= (sqrtf(fabsf(d[m - 1])) * sqrtf(fabsf(d[m]))) * eps) {
                e[m - 1] = 0.0f;
                goto L30;
            }
        }
    }
    m = n;
L30:
    l = l1;
    lend = m;
    l1 = m + 1;
    if (lend == l) goto L10;
    {
        float anorm = 0.0f;
        for (int i = l; i <= lend; ++i) anorm = fmaxf(anorm, fabsf(d[i - 1]));
        for (int i = l; i <= lend - 1; ++i) anorm = fmaxf(anorm, fabsf(e[i - 1]));
        if (anorm == 0.0f) goto L10;
    }
    if (fabsf(d[lend - 1]) < fabsf(d[l - 1])) { int t = lend; lend = l; l = t; }

    if (lend > l) {
L40:
        if (l != lend) {
            bool found = false;
            for (m = l; m <= lend - 1; ++m) {
                float tst = e[m - 1] * e[m - 1];
                if (tst <= (eps2 * fabsf(d[m - 1])) * fabsf(d[m]) + safmin) { found = true; break; }
            }
            if (!found) m = lend;
        } else m = lend;
        if (m < lend) e[m - 1] = 0.0f;
        p = d[l - 1];
        if (m == l) goto L80;
        if (m == l + 1) {
            slaev2(d[l - 1], e[l - 1], d[l], rt1, rt2, c, s);
            for (int i = 0; i < n; ++i) {
                float tmp = z[i][l];
                z[i][l]     = c * tmp - s * z[i][l - 1];
                z[i][l - 1] = s * tmp + c * z[i][l - 1];
            }
            d[l - 1] = rt1; d[l] = rt2; e[l - 1] = 0.0f;
            l += 2;
            if (l <= lend) goto L40;
            goto L140;
        }
        if (jtot == nmaxit) goto L140;
        ++jtot;
        g = (d[l] - p) / (2.0f * e[l - 1]);
        r = slapy2(g, 1.0f);
        g = (d[m - 1] - p) + e[l - 1] / (g + f_sign(r, g));
        s = 1.0f; c = 1.0f; p = 0.0f;
        for (int i = m - 1; i >= l; --i) {
            f = s * e[i - 1];
            b = c * e[i - 1];
            slartg(g, f, c, s, r);
            if (i != m - 1) e[i] = r;
            g = d[i] - p;
            r = (d[i - 1] - g) * s + (2.0f * c) * b;
            p = s * r;
            d[i] = g + p;
            g = c * r - b;
            wc[i - 1] = c;
            wsn[i - 1] = -s;
        }
        for (int jj = m - 1; jj >= l; --jj) {
            float ct = wc[jj - 1], st = wsn[jj - 1];
            for (int i = 0; i < n; ++i) {
                float tmp = z[i][jj];
                z[i][jj]     = ct * tmp - st * z[i][jj - 1];
                z[i][jj - 1] = st * tmp + ct * z[i][jj - 1];
            }
        }
        d[l - 1] -= p;
        e[l - 1] = g;
        goto L40;
L80:
        d[l - 1] = p;
        ++l;
        if (l <= lend) goto L40;
        goto L140;
    } else {
L90:
        if (l != lend) {
            bool found = false;
            for (m = l; m >= lend + 1; --m) {
                float tst = e[m - 2] * e[m - 2];
                if (tst <= (eps2 * fabsf(d[m - 1])) * fabsf(d[m - 2]) + safmin) { found = true; break; }
            }
            if (!found) m = lend;
        } else m = lend;
        if (m > lend) e[m - 2] = 0.0f;
        p = d[l - 1];
        if (m == l) goto L130;
        if (m == l - 1) {
            slaev2(d[l - 2], e[l - 2], d[l - 1], rt1, rt2, c, s);
            for (int i = 0; i < n; ++i) {
                float tmp = z[i][l - 1];
                z[i][l - 1] = c * tmp - s * z[i][l - 2];
                z[i][l - 2] = s * tmp + c * z[i][l - 2];
            }
            d[l - 2] = rt1; d[l - 1] = rt2; e[l - 2] = 0.0f;
            l -= 2;
            if (l >= lend) goto L90;
            goto L140;
        }
        if (jtot == nmaxit) goto L140;
        ++jtot;
        g = (d[l - 2] - p) / (2.0f * e[l - 2]);
        r = slapy2(g, 1.0f);
        g = (d[m - 1] - p) + e[l - 2] / (g + f_sign(r, g));
        s = 1.0f; c = 1.0f; p = 0.0f;
        for (int i = m; i <= l - 1; ++i) {
            f = s * e[i - 1];
            b = c * e[i - 1];
            slartg(g, f, c, s, r);
            if (i != m) e[i - 2] = r;
            g = d[i - 1] - p;
            r = (d[i] - g) * s + (2.0f * c) * b;
            p = s * r;
            d[i - 1] = g + p;
            g = c * r - b;
            wc[i - 1] = c;
            wsn[i - 1] = s;
        }
        for (int jj = m; jj <= l - 1; ++jj) {
            float ct = wc[jj - 1], st = wsn[jj - 1];
            for (int i = 0; i < n; ++i) {
                float tmp = z[i][jj];
                z[i][jj]     = ct * tmp - st * z[i][jj - 1];
                z[i][jj - 1] = st * tmp + ct * z[i][jj - 1];
            }
        }
        d[l - 1] -= p;
        e[l - 2] = g;
        goto L90;
L130:
        d[l - 1] = p;
        --l;
        if (l >= lend) goto L90;
        goto L140;
    }
L140:
    if (jtot < nmaxit) goto L10;
L160:
    for (int ii = 2; ii <= n; ++ii) {
        int i = ii - 1, kk = i;
        float pp = d[i - 1];
        for (int j = ii; j <= n; ++j)
            if (d[j - 1] < pp) { kk = j; pp = d[j - 1]; }
        if (kk != i) {
            d[kk - 1] = d[i - 1];
            d[i - 1] = pp;
            for (int row = 0; row < n; ++row) {
                float t2 = z[row][i - 1];
                z[row][i - 1] = z[row][kk - 1];
                z[row][kk - 1] = t2;
            }
        }
    }
}

__device__ void ssyevd3(float a11, float a21, float a31,
                        float a22, float a32, float a33, float V[3][3]) {
    float tau1, v2, e1;
    float alpha = a21;
    float xnorm = fabsf(a31);
    if (xnorm == 0.0f) {
        tau1 = 0.0f; v2 = 0.0f; e1 = a21;
    } else {
        float beta = -f_sign(slapy2(alpha, xnorm), alpha);
        tau1 = (beta - alpha) / beta;
        float t = 1.0f / (alpha - beta);
        v2 = a31 * t;
        e1 = beta;
        float w1 = tau1 * a22;
        float w2 = tau1 * a32;
        float temp2 = a32 * v2;
        w1 = w1 + tau1 * temp2;
        float temp1 = tau1 * v2;
        w2 = w2 + temp1 * a33;
        float dot = w1;
        dot = dot + w2 * v2;
        float alpha2 = (-0.5f * tau1) * dot;
        w1 = w1 + alpha2;
        w2 = w2 + alpha2 * v2;
        a22 = (a22 - w1) - w1;
        a32 = (a32 - v2 * w1) - w2;
        a33 = (a33 - v2 * w2) - w2 * v2;
    }
    float d[3] = { a11, a22, a33 };
    float e[2] = { e1, a32 };
    float z[3][3];
    ssteqr3(d, e, z);
    for (int j = 0; j < 3; ++j) {
        float wj = z[1][j];
        wj = wj + z[2][j] * v2;
        float temp = (-tau1) * wj;
        V[0][j] = z[0][j];
        V[1][j] = z[1][j] + temp;
        V[2][j] = z[2][j] + v2 * temp;
    }
}

// Per-query geometry: r, scale, cov, ssyevd, rotate. Runs on one thread.
__device__ void geom_body(const float *__restrict__ posf, const int *__restrict__ ord,
                          int q, int k, float *__restrict__ rrot) {
    float qx = posf[3 * q], qy = posf[3 * q + 1], qz = posf[3 * q + 2];
    float rx[16], ry[16], rz[16], nrm[16];
    for (int j = 0; j < k; ++j) {
        int s = ord[j];
        rx[j] = posf[3 * s] - qx;
        ry[j] = posf[3 * s + 1] - qy;
        rz[j] = posf[3 * s + 2] - qz;
        float t = rx[j] * rx[j];
        t = t + ry[j] * ry[j];
        t = t + rz[j] * rz[j];
        nrm[j] = sqrtf(t);
    }
    float scale = nrm[0];
    for (int j = 1; j < k; ++j) scale = fmaxf(scale, nrm[j]);
    float sc = scale + 1e-8f;
    for (int j = 0; j < k; ++j) {
        rx[j] = rx[j] / sc;
        ry[j] = ry[j] / sc;
        rz[j] = rz[j] / sc;
    }
    float c00 = 0.f, c01 = 0.f, c02 = 0.f, c11 = 0.f, c12 = 0.f, c22 = 0.f;
    for (int j = 0; j < k; ++j) {
        c00 = c00 + rx[j] * rx[j];
        c01 = c01 + rx[j] * ry[j];
        c02 = c02 + rx[j] * rz[j];
        c11 = c11 + ry[j] * ry[j];
        c12 = c12 + ry[j] * rz[j];
        c22 = c22 + rz[j] * rz[j];
    }
    float fk = (float)k;
    c00 = c00 / fk; c01 = c01 / fk; c02 = c02 / fk;
    c11 = c11 / fk; c12 = c12 / fk; c22 = c22 / fk;
    float V[3][3];
    ssyevd3(c00, c01, c02, c11, c12, c22, V);
    for (int j = 0; j < k; ++j) {
        for (int col = 0; col < 3; ++col) {
            float a = rx[j] * V[0][col];
            a = a + ry[j] * V[1][col];
            a = a + rz[j] * V[2][col];
            rrot[q * 48 + j * 3 + col] = a;
        }
    }
}

// Standalone geometry: one THREAD per query (64 eigensolves per wave).
__global__ __launch_bounds__(256) void geom_kernel(
    const float *__restrict__ posf, const int *__restrict__ idx,
    int Q, int k, float *__restrict__ rrot) {
    int q = blockIdx.x * 256 + threadIdx.x;
    if (q >= Q) return;
    geom_body(posf, idx + (size_t)q * k, q, k, rrot);
}

// ---------------------------------------------------------------------------

// Also zeroes the B3-tail dot-product scalar (stream start; nothing else
// touches the last 8B of the tbuf region -- see workspace notes).
__global__ void prep_kernel(const float *__restrict__ posf, float4 *__restrict__ pos4,
                            double *__restrict__ zscalar) {
    int i = blockIdx.x * 256 + threadIdx.x;
    if (i == 0) *zscalar = 0.0;
    if (i >= 32768) return;
    float x = posf[3 * i], y = posf[3 * i + 1], z = posf[3 * i + 2];
    float t = x * x;
    t = t + y * y;
    t = t + z * z;
    pos4[i] = make_float4(x, y, z, t);
}

// Sorted-top-16 insert (lanes 0..15 hold the list ascending by (dist,idx)).
// No LDS-pipe ops: extracted candidate + kth via v_readlane (wave-uniform),
// list shift via DPP row_shr:1 (list lives entirely in row 0, lanes 0-15).
// Candidates arrive in increasing j within a wave, d==kth excluded,
// insert-after-equal -> identical semantics to reference lex top-16.
__device__ __forceinline__ void insert16(float d, int jbase, int lane,
                                         float &ld, int &li, float &kth) {
    unsigned long long mask = __ballot(d < kth);
    while (mask) {
        int src = __ffsll(mask) - 1;
        mask &= mask - 1;
        float dv = __int_as_float(__builtin_amdgcn_readlane(__float_as_int(d), src));
        int jv = jbase + src;
        if (dv < kth) {
            unsigned long long lm = __ballot((lane < 16) && (ld <= dv));
            int p2 = __popcll(lm);
            float sd = __int_as_float(__builtin_amdgcn_update_dpp(
                0, __float_as_int(ld), 0x111, 0xf, 0xf, true));
            int si = __builtin_amdgcn_update_dpp(0, li, 0x111, 0xf, 0xf, true);
            if (lane < 16) {
                if (lane == p2) { ld = dv; li = jv; }
                else if (lane > p2) { ld = sd; li = si; }
            }
            kth = __int_as_float(__builtin_amdgcn_readlane(__float_as_int(ld), 15));
        }
    }
}

// Init the top-16 list from 64 candidates via full 64-lane bitonic sort on
// lex key (dist, idx) ascending. Equivalent to sequentially inserting the 64
// distinct (d, jbase+lane) pairs into an empty list: lanes 0-15 = 16
// lex-smallest ascending; kth = lane 15. idx uniqueness -> total order.
__device__ __forceinline__ void sort64_init(float d, int jbase, int lane,
                                            float &ld, int &li, float &kth) {
    float v = d;
    int vi = jbase + lane;
#pragma unroll
    for (int k2 = 2; k2 <= 64; k2 <<= 1) {
#pragma unroll
        for (int j2 = k2 >> 1; j2 > 0; j2 >>= 1) {
            float ov = __shfl_xor(v, j2);
            int oi = __shfl_xor(vi, j2);
            bool oless = (ov < v) || (ov == v && oi < vi);
            bool dir = ((lane & k2) == 0);        // ascending block?
            bool keepmin = (((lane & j2) == 0) == dir);
            bool take = keepmin ? oless : !oless;
            if (take) { v = ov; vi = oi; }
        }
    }
    if (lane < 16) { ld = v; li = vi; }
    kth = __int_as_float(__builtin_amdgcn_readlane(__float_as_int(v), 15));
}

// Process one 256-candidate tile held in registers P0..P3 at base BB.
// Pre-ballot tile skip: kth only tightens, so if no lane's min passes now,
// none of the 4 sub-tiles can insert. Semantics equal to always-insert.
#define SCAN_PROC(P0, P1, P2, P3, BB)                                        \
    do {                                                                     \
        float m0 = fmaf(qp.x, (P0).x, 0.0f);                                 \
        m0 = fmaf(qp.y, (P0).y, m0);                                         \
        m0 = fmaf(qp.z, (P0).z, m0);                                         \
        float d0 = (qp.w + (P0).w) - 2.0f * m0;                              \
        float m1 = fmaf(qp.x, (P1).x, 0.0f);                                 \
        m1 = fmaf(qp.y, (P1).y, m1);                                         \
        m1 = fmaf(qp.z, (P1).z, m1);                                         \
        float d1 = (qp.w + (P1).w) - 2.0f * m1;                              \
        float m2 = fmaf(qp.x, (P2).x, 0.0f);                                 \
        m2 = fmaf(qp.y, (P2).y, m2);                                         \
        m2 = fmaf(qp.z, (P2).z, m2);                                         \
        float d2 = (qp.w + (P2).w) - 2.0f * m2;                              \
        float m3 = fmaf(qp.x, (P3).x, 0.0f);                                 \
        m3 = fmaf(qp.y, (P3).y, m3);                                         \
        m3 = fmaf(qp.z, (P3).z, m3);                                         \
        float d3 = (qp.w + (P3).w) - 2.0f * m3;                              \
        float dmin = fminf(fminf(d0, d1), fminf(d2, d3));                    \
        if (first || __ballot(dmin < kth)) {                                 \
            if (first) {                                                     \
                sort64_init(d0, (BB), lane, ld, li, kth);                    \
                first = false;                                               \
            } else {                                                         \
                insert16(d0, (BB), lane, ld, li, kth);                       \
            }                                                                \
            insert16(d1, (BB) + 64, lane, ld, li, kth);                      \
            insert16(d2, (BB) + 128, lane, ld, li, kth);                     \
            insert16(d3, (BB) + 192, lane, ld, li, kth);                     \
        }                                                                    \
    } while (0)

// Wave-level scan of candidate range [start,end): 2-deep ping-pong prefetch
// (no register-copy rotation), sort-init warm-up, pre-ballot tile skip.
// Tiles processed in strictly increasing base per wave -- identical
// candidate order to the r5-verified kernel. Per-wave sorted top-16 out.
__device__ __forceinline__ void scan_range(
    const float4 *__restrict__ pos4, float4 qp, int start, int end, int lane,
    float &ld, int &li, float &kth) {
    const float FINF = 3.0e38f;
    int base = start;
    bool first = true;
    float4 c0, c1, c2, c3, n0, n1, n2, n3;
    if (base + 256 <= end) {
        c0 = pos4[base + lane];
        c1 = pos4[base + 64 + lane];
        c2 = pos4[base + 128 + lane];
        c3 = pos4[base + 192 + lane];
        for (;;) {
            int nb = base + 1024;
            bool nh = (nb + 256 <= end);
            if (nh) {
                n0 = pos4[nb + lane];
                n1 = pos4[nb + 64 + lane];
                n2 = pos4[nb + 128 + lane];
                n3 = pos4[nb + 192 + lane];
            }
            SCAN_PROC(c0, c1, c2, c3, base);
            if (!nh) { base = nb; break; }
            int nb2 = nb + 1024;
            bool nh2 = (nb2 + 256 <= end);
            if (nh2) {
                c0 = pos4[nb2 + lane];
                c1 = pos4[nb2 + 64 + lane];
                c2 = pos4[nb2 + 128 + lane];
                c3 = pos4[nb2 + 192 + lane];
            }
            SCAN_PROC(n0, n1, n2, n3, nb);
            base = nb2;
            if (!nh2) break;
        }
    }
    if (base < end) {
#pragma unroll
        for (int k2 = 0; k2 < 4; ++k2) {
            int j = base + k2 * 64 + lane;
            float dd = FINF;
            if (j < end) {
                float4 p = pos4[j];
                float m = fmaf(qp.x, p.x, 0.0f);
                m = fmaf(qp.y, p.y, m);
                m = fmaf(qp.z, p.z, m);
                dd = (qp.w + p.w) - 2.0f * m;
            }
            insert16(dd, base + k2 * 64, lane, ld, li, kth);
        }
    }
}

// Two-stage bitonic merge of four sorted 16-lists (md/mi[64]) -> sorted 16
// in lanes 0-15 (v2, vi2). Lex key (dist,idx) ascending. r1-verified.
__device__ __forceinline__ void merge4x16(const float *md, const int *mi,
                                          int lane, float &v2, int &vi2) {
    int l16 = lane & 15;
    int srcA = (lane >> 5) * 32 + ((lane & 16) ? (16 + (15 - l16)) : l16);
    float v = md[srcA];
    int vi = mi[srcA];
    for (int off = 16; off > 0; off >>= 1) {
        float ov = __shfl_xor(v, off);
        int oi = __shfl_xor(vi, off);
        bool oless = (ov < v) || (ov == v && oi < vi);
        bool take = (lane & off) ? (!oless) : oless;
        if (take) { v = ov; vi = oi; }
    }
    int src2 = (lane < 16) ? lane : (63 - lane);
    v2 = __shfl(v, src2);
    vi2 = __shfl(vi, src2);
    for (int off = 16; off > 0; off >>= 1) {
        float ov = __shfl_xor(v2, off);
        int oi = __shfl_xor(vi2, off);
        bool oless = (ov < v2) || (ov == v2 && oi < vi2);
        bool take = (lane & off) ? (!oless) : oless;
        if (take) { v2 = ov; vi2 = oi; }
    }
}

// k=16 kNN. 1 query/block, 4 waves, 4 candidates/lane/iter; wave w scans
// base=w*256 stride 1024 -- identical candidate partition/order to the
// verified r5 kernel. DOGEOM=1 instantiation (small Q) runs the lane-0
// geometry tail in-block; DOGEOM=0 (hot large-Q path) stays lean.
template <int DOGEOM>
__global__ __launch_bounds__(256) void knng16_kernel(
    const float4 *__restrict__ pos4, const float *__restrict__ posf,
    int S, int *__restrict__ idx_out, float *__restrict__ rrot) {
    __shared__ float md[64];
    __shared__ int mi[64];
    __shared__ int ord[16];
    int q = blockIdx.x;
    int tid = threadIdx.x;
    int lane = tid & 63;
    int w = tid >> 6;
    float4 qp = pos4[q];
    const float FINF = 3.0e38f;
    float ld = FINF;
    int li = 0x7fffffff;
    float kth = FINF;
    scan_range(pos4, qp, w * 256, S, lane, ld, li, kth);
    if (lane < 16) { md[w * 16 + lane] = ld; mi[w * 16 + lane] = li; }
    __syncthreads();
    if (w == 0) {
        float v2; int vi2;
        merge4x16(md, mi, lane, v2, vi2);
        if (lane < 16) {
            idx_out[q * 16 + lane] = vi2;
            if (DOGEOM) ord[lane] = vi2;
        }
        if (DOGEOM && lane == 0) geom_body(posf, ord, q, 16, rrot);
    }
}

// Small-S (S <= 64) kNN + in-block geometry; one wave per query (small Q).
__global__ __launch_bounds__(64) void knngs_kernel(
    const float4 *__restrict__ pos4, const float *__restrict__ posf,
    int S, int k, int *__restrict__ idx_out, float *__restrict__ rrot) {
    __shared__ int ord[16];
    int q = blockIdx.x;
    int lane = threadIdx.x;
    float4 qp = pos4[q];
    const float FINF = 3.0e38f;
    float dist = FINF;
    if (lane < S) {
        float4 p = pos4[lane];
        float m = fmaf(qp.x, p.x, 0.0f);
        m = fmaf(qp.y, p.y, m);
        m = fmaf(qp.z, p.z, m);
        dist = (qp.w + p.w) - 2.0f * m;
    }
    bool used = false;
    for (int r = 0; r < k; ++r) {
        float v = used ? FINF : dist;
        int vid = (used || lane >= S) ? 0x7fffffff : lane;
        for (int off = 32; off > 0; off >>= 1) {
            float ov = __shfl_down(v, off);
            int oid = __shfl_down(vid, off);
            if (ov < v || (ov == v && oid < vid)) { v = ov; vid = oid; }
        }
        vid = __shfl(vid, 0);
        if (lane == 0) { idx_out[q * k + r] = vid; ord[r] = vid; }
        if (lane == vid) used = true;
    }
    if (lane == 0) geom_body(posf, ord, q, k, rrot);
}

__device__ __forceinline__ void compute_phi(const float *rrot, int q, int tid,
                                            double phi[45]) {
    double x = (double)rrot[q * 48 + tid * 3 + 0];
    double y = (double)rrot[q * 48 + tid * 3 + 1];
    double z = (double)rrot[q * 48 + tid * 3 + 2];
    double px[5], py[3], pz[3];
    px[0] = 1.0; px[1] = x; px[2] = x * x; px[3] = px[2] * x; px[4] = px[3] * x;
    py[0] = 1.0; py[1] = y; py[2] = y * y;
    pz[0] = 1.0; pz[1] = z; pz[2] = z * z;
#pragma unroll
    for (int n2 = 0; n2 < 5; ++n2)
#pragma unroll
        for (int l2 = 0; l2 < 3; ++l2)
#pragma unroll
            for (int m2 = 0; m2 < 3; ++m2)
                phi[n2 * 9 + l2 * 3 + m2] = (px[n2] * py[l2]) * pz[m2];
}

// Generic per-query fused conv (B0-L1, C=4).
__global__ __launch_bounds__(256) void feat_kernel(
    const float *__restrict__ rrot, const int *__restrict__ idx, int k,
    const double *__restrict__ fin64, const float *__restrict__ fin32, int C,
    const float *__restrict__ W, const float *__restrict__ bias, int O,
    double *__restrict__ fout) {
    __shared__ double phi_sh[16][45];
    __shared__ int idx_sh[16];
    __shared__ double red_sh[256];
    extern __shared__ double dyn[];
    double *nf = dyn;            // [16][C]
    double *t = dyn + 16 * C;    // [9][C]
    int q = blockIdx.x;
    int tid = threadIdx.x;
    int OT = O < 256 ? O : 256;
    int nseg = 256 / OT;
    int o = tid % OT;
    int seg = tid / OT;
    int cseg = C / nseg;
    int c0 = seg * cseg, c1 = c0 + cseg;
    if (tid < k) {
        idx_sh[tid] = idx[q * k + tid];
        double phi[45];
        compute_phi(rrot, q, tid, phi);
#pragma unroll
        for (int b2 = 0; b2 < 45; ++b2) phi_sh[tid][b2] = phi[b2];
    }
    __syncthreads();
    for (int e2 = tid; e2 < k * C; e2 += 256) {
        int j = e2 / C, cc = e2 - j * C;
        size_t src = (size_t)idx_sh[j] * C + cc;
        nf[j * C + cc] = fin32 ? (double)fin32[src] : fin64[src];
    }
    __syncthreads();
    double accp = 0.0;
    for (int ch = 0; ch < 45; ch += 9) {
        for (int e2 = tid; e2 < 9 * C; e2 += 256) {
            int b2 = e2 / C, cc = e2 - b2 * C;
            double a2 = 0.0;
            for (int j = 0; j < k; ++j) a2 = fma(phi_sh[j][ch + b2], nf[j * C + cc], a2);
            t[e2] = a2 / (double)k;
        }
        __syncthreads();
        double a0 = 0.0, a1 = 0.0;
        for (int b2 = 0; b2 < 9; ++b2) {
            const float *wp = W + (size_t)(ch + b2) * C * O + o;
            const double *tp = t + b2 * C;
            int cc = c0;
            for (; cc + 2 <= c1; cc += 2) {
                a0 = fma(tp[cc],     (double)wp[(size_t)cc * O], a0);
                a1 = fma(tp[cc + 1], (double)wp[(size_t)(cc + 1) * O], a1);
            }
            for (; cc < c1; ++cc) a0 = fma(tp[cc], (double)wp[(size_t)cc * O], a0);
        }
        accp += a0 + a1;
        __syncthreads();
    }
    red_sh[tid] = accp;
    __syncthreads();
    if (tid < OT) {
        double v = 0.0;
        for (int s2 = 0; s2 < nseg; ++s2) v += red_sh[tid + s2 * OT];
        v += (double)bias[tid];
        fout[(size_t)q * O + tid] = v > 0.0 ? v : 0.0;
    }
}

// Specialized C=64, O=64, k=16 fused conv (B0-L2), 2 queries per block.
__global__ __launch_bounds__(256) void feat64_kernel(
    const float *__restrict__ rrot, const int *__restrict__ idx,
    const double *__restrict__ fin, const float *__restrict__ W,
    const float *__restrict__ bias, int Q, double *__restrict__ fout) {
    __shared__ double phi_sh[2][16][45];
    __shared__ int idx_sh[2][16];
    __shared__ double nf[2][16][64];
    __shared__ double t[2][9][64];
    __shared__ double red[16][64];
    int q0 = blockIdx.x * 2;
    int nq = (Q - q0) < 2 ? (Q - q0) : 2;
    int tid = threadIdx.x;
    int tx = tid & 15;
    int seg = tid >> 4;
    int o0 = tx * 4;
    int cbase = seg * 4;
    if (tid < 32) {
        int qi = tid >> 4, j = tid & 15;
        int qq = q0 + (qi < nq ? qi : 0);
        idx_sh[qi][j] = idx[qq * 16 + j];
        double phi[45];
        compute_phi(rrot, qq, j, phi);
#pragma unroll
        for (int b2 = 0; b2 < 45; ++b2) phi_sh[qi][j][b2] = phi[b2];
    }
    __syncthreads();
    for (int e2 = tid; e2 < 2 * 16 * 64; e2 += 256) {
        int qi = e2 >> 10, j = (e2 >> 6) & 15, cc = e2 & 63;
        nf[qi][j][cc] = fin[(size_t)idx_sh[qi][j] * 64 + cc];
    }
    __syncthreads();
    double acc[2][4] = {{0.0, 0.0, 0.0, 0.0}, {0.0, 0.0, 0.0, 0.0}};
    for (int ch = 0; ch < 45; ch += 9) {
        for (int e2 = tid; e2 < 2 * 9 * 64; e2 += 256) {
            int qi = e2 / 576, rem = e2 - qi * 576;
            int b2 = rem >> 6, cc = rem & 63;
            double a2 = 0.0;
#pragma unroll
            for (int j = 0; j < 16; ++j) a2 = fma(phi_sh[qi][j][ch + b2], nf[qi][j][cc], a2);
            t[qi][b2][cc] = a2 * 0.0625;
        }
        __syncthreads();
#pragma unroll
        for (int b2 = 0; b2 < 9; ++b2) {
            const float *wrow = W + ((size_t)(ch + b2) * 64 + cbase) * 64 + o0;
#pragma unroll
            for (int i = 0; i < 4; ++i) {
                float4 wv = *(const float4 *)(wrow + (size_t)i * 64);
                double w0 = (double)wv.x, w1 = (double)wv.y;
                double w2 = (double)wv.z, w3 = (double)wv.w;
                double tv0 = t[0][b2][cbase + i];
                double tv1 = t[1][b2][cbase + i];
                acc[0][0] = fma(tv0, w0, acc[0][0]);
                acc[0][1] = fma(tv0, w1, acc[0][1]);
                acc[0][2] = fma(tv0, w2, acc[0][2]);
                acc[0][3] = fma(tv0, w3, acc[0][3]);
                acc[1][0] = fma(tv1, w0, acc[1][0]);
                acc[1][1] = fma(tv1, w1, acc[1][1]);
                acc[1][2] = fma(tv1, w2, acc[1][2]);
                acc[1][3] = fma(tv1, w3, acc[1][3]);
            }
        }
        __syncthreads();
    }
    for (int qi = 0; qi < nq; ++qi) {
        red[seg][o0 + 0] = acc[qi][0];
        red[seg][o0 + 1] = acc[qi][1];
        red[seg][o0 + 2] = acc[qi][2];
        red[seg][o0 + 3] = acc[qi][3];
        __syncthreads();
        if (tid < 64) {
            double v = 0.0;
#pragma unroll
            for (int s2 = 0; s2 < 16; ++s2) v += red[s2][tid];
            v += (double)bias[tid];
            fout[(size_t)(q0 + qi) * 64 + tid] = v > 0.0 ? v : 0.0;
        }
        __syncthreads();
    }
}

// Stage 1 (small Q): t[q-q0][45*C], grid (qcount, 5 basis chunks of 9).
// blockIdx.y==0 blocks also zero this q's fout row (replaces hipMemsetAsync;
// gemm's atomics run in a strictly later kernel, so no race).
// fbias != nullptr: fin holds the previous gemm's RAW accumulator; apply
// v = relu(fin + bias) on read -- identical f64 op order to a finalize pass.
__global__ __launch_bounds__(256) void t_kernel(
    const float *__restrict__ rrot, const int *__restrict__ idx, int k,
    const double *__restrict__ fin, const float *__restrict__ fbias, int C,
    int q0, double *__restrict__ tbuf, double *__restrict__ fout, int O) {
    __shared__ double phi_sh[16][45];
    __shared__ int idx_sh[16];
    extern __shared__ double nf[];  // [16][C]
    int q = q0 + blockIdx.x;
    int bch = blockIdx.y * 9;
    int tid = threadIdx.x;
    if (blockIdx.y == 0) {
        for (int i = tid; i < O; i += 256) fout[(size_t)q * O + i] = 0.0;
    }
    if (tid < k) {
        idx_sh[tid] = idx[q * k + tid];
        double phi[45];
        compute_phi(rrot, q, tid, phi);
#pragma unroll
        for (int b2 = 0; b2 < 45; ++b2) phi_sh[tid][b2] = phi[b2];
    }
    __syncthreads();
    for (int e2 = tid; e2 < k * C; e2 += 256) {
        int j = e2 / C, cc = e2 - j * C;
        double v = fin[(size_t)idx_sh[j] * C + cc];
        if (fbias) {
            v = v + (double)fbias[cc];
            v = v > 0.0 ? v : 0.0;
        }
        nf[j * C + cc] = v;
    }
    __syncthreads();
    int K = 45 * C;
    for (int e2 = tid; e2 < 9 * C; e2 += 256) {
        int b2 = bch + e2 / C, cc = e2 % C;
        double a2 = 0.0;
        for (int j = 0; j < k; ++j) a2 = fma(phi_sh[j][b2], nf[j * C + cc], a2);
        tbuf[(size_t)blockIdx.x * K + b2 * C + cc] = a2 / (double)k;
    }
}

// Stage 2: K-split GEMM, f64 atomics straight into acc (= fout region).
// Unroll-8, 8 independent accumulators, double2 tp loads (tbuf 16B-aligned,
// kchunk forced to a multiple of 8 by the launcher).
__global__ __launch_bounds__(256) void gemm_kernel(
    const double *__restrict__ tbuf, const float *__restrict__ W,
    int K, int O, int q0, int q1, int kchunk, double *__restrict__ acc) {
    int OT = O < 256 ? O : 256;
    int qpb = 256 / OT;
    int tid = threadIdx.x;
    int o = blockIdx.x * OT + (tid % OT);
    int q = q0 + blockIdx.y * qpb + tid / OT;
    if (q >= q1) return;
    int k0 = blockIdx.z * kchunk;
    if (k0 >= K) return;
    int kend = min(k0 + kchunk, K);
    const double *tp = tbuf + (size_t)(q - q0) * K;
    const float *wp = W + (size_t)k0 * O + o;
    double a0 = 0.0, a1 = 0.0, a2 = 0.0, a3 = 0.0;
    double a4 = 0.0, a5 = 0.0, a6 = 0.0, a7 = 0.0;
    int kk = k0;
    for (; kk + 8 <= kend; kk += 8) {
        double2 t01 = *(const double2 *)(tp + kk);
        double2 t23 = *(const double2 *)(tp + kk + 2);
        double2 t45 = *(const double2 *)(tp + kk + 4);
        double2 t67 = *(const double2 *)(tp + kk + 6);
        float w0 = wp[0];
        float w1 = wp[(size_t)O];
        float w2 = wp[2 * (size_t)O];
        float w3 = wp[3 * (size_t)O];
        float w4 = wp[4 * (size_t)O];
        float w5 = wp[5 * (size_t)O];
        float w6 = wp[6 * (size_t)O];
        float w7 = wp[7 * (size_t)O];
        a0 = fma(t01.x, (double)w0, a0);
        a1 = fma(t01.y, (double)w1, a1);
        a2 = fma(t23.x, (double)w2, a2);
        a3 = fma(t23.y, (double)w3, a3);
        a4 = fma(t45.x, (double)w4, a4);
        a5 = fma(t45.y, (double)w5, a5);
        a6 = fma(t67.x, (double)w6, a6);
        a7 = fma(t67.y, (double)w7, a7);
        wp += 8 * (size_t)O;
    }
    for (; kk < kend; ++kk) {
        a0 = fma(tp[kk], (double)wp[0], a0);
        wp += (size_t)O;
    }
    double s = ((a0 + a1) + (a2 + a3)) + ((a4 + a5) + (a6 + a7));
    atomicAdd(&acc[(size_t)q * O + o], s);
}

__global__ void resid0_kernel(const float *__restrict__ chanf, const float *__restrict__ p,
                              const double *__restrict__ x, double *__restrict__ fout) {
    int i = blockIdx.x * 256 + threadIdx.x;
    if (i >= 2435 * 64) return;
    int q = i >> 6, o = i & 63;
    const float *f = chanf + 4 * q;
    float c = fmaf(f[0], p[o], 0.0f);
    c = fmaf(f[1], p[64 + o], c);
    c = fmaf(f[2], p[128 + o], c);
    c = fmaf(f[3], p[192 + o], c);
    double v = x[i] + (double)c;
    fout[i] = v > 0.0 ? v : 0.0;
}

// Fused finalize + residual: x = relu(acc + bias); fout = relu(x + fin@p).
// Identical op order to finalize followed by the residual pass.
__global__ void resid64f_kernel(const float *__restrict__ bias,
                                const double *__restrict__ acc,
                                const double *__restrict__ fin, int Cin,
                                const float *__restrict__ p,
                                int Q, int Cout, double *__restrict__ fout) {
    int i = blockIdx.x * blockDim.x + threadIdx.x;
    if (i >= Q * Cout) return;
    int q = i / Cout, o = i - q * Cout;
    double v = acc[i] + (double)bias[o];
    double x = v > 0.0 ? v : 0.0;
    double a = 0.0;
    for (int c = 0; c < Cin; ++c) a = fma(fin[q * Cin + c], (double)p[c * Cout + o], a);
    double r = x + a;
    fout[i] = r > 0.0 ? r : 0.0;
}

// B3 tail stage A (16 blocks): block b owns outputs i in [32b, 32b+32);
// 8 threads per output each sum 32 of the 256 c-terms (coalesced p reads);
// LDS reduce -> r_i = relu(relu(acc+bias)+dot); block reduces
// sum(r_i * hw_i) and atomicAdds into the f64 scalar (zeroed by prep).
// f64 reassociation within the feature-path slack.
__global__ __launch_bounds__(256) void rvdot_kernel(
    const float *__restrict__ bias, const double *__restrict__ acc,
    const double *__restrict__ fin, int Cin, const float *__restrict__ p,
    const float *__restrict__ hw, double *__restrict__ scalar) {
    __shared__ double part[256];
    __shared__ double rvs[32];
    int tid = threadIdx.x;
    int i = blockIdx.x * 32 + (tid >> 3);
    int cp = tid & 7;
    int clen = Cin / 8;
    int c0 = cp * clen;
    double a = 0.0;
    for (int c = c0; c < c0 + clen; ++c)
        a = fma(fin[c], (double)p[c * 512 + i], a);
    part[tid] = a;
    __syncthreads();
    if (cp == 0) {
        double dot = ((part[tid] + part[tid + 1]) + (part[tid + 2] + part[tid + 3]))
                   + ((part[tid + 4] + part[tid + 5]) + (part[tid + 6] + part[tid + 7]));
        double v = acc[i] + (double)bias[i];
        double x = v > 0.0 ? v : 0.0;
        double r = x + dot;
        r = r > 0.0 ? r : 0.0;
        rvs[tid >> 3] = r * (double)hw[i];
    }
    __syncthreads();
    if (tid == 0) {
        double s = 0.0;
        for (int j = 0; j < 32; ++j) s += rvs[j];
        atomicAdd(scalar, s);
    }
}

// B3 tail stage B: out = (float)(scalar + hb). Single 8-byte read.
__global__ void outhead_kernel(const double *__restrict__ scalar,
                               const float *__restrict__ hb,
                               float *__restrict__ out) {
    if (threadIdx.x == 0 && blockIdx.x == 0)
        out[0] = (float)(*scalar + (double)hb[0]);
}

// ---------------------------------------------------------------------------

extern "C" void kernel_launch(void *const *d_in, const int *in_sizes, int n_in,
                              void *d_out, int out_size, void *d_ws, size_t ws_size,
                              hipStream_t stream) {
    (void)in_sizes; (void)n_in; (void)out_size;

    const float *posf = (const float *)d_in[0];
    const float *chanf = (const float *)d_in[1];
    const float *W[8], *B[8];
    for (int li = 1; li <= 7; ++li) {
        W[li] = (const float *)d_in[2 + 2 * (li - 1)];
        B[li] = (const float *)d_in[3 + 2 * (li - 1)];
    }
    const float *P[5];
    for (int bi = 1; bi <= 4; ++bi) P[bi] = (const float *)d_in[15 + bi];
    const float *hw = (const float *)d_in[20];
    const float *hb = (const float *)d_in[21];

    // workspace layout (bytes)
    char *wsb = (char *)d_ws;
    double *B1   = (double *)(wsb + 0);            // 2435*64 f64 = 1,246,720
    double *B2   = (double *)(wsb + 1246720);
    double *B3   = (double *)(wsb + 2493440);
    float *rrot  = (float *)(wsb + 3740160);       // 2435*48 f32 = 467,520
    int *idx     = (int *)(wsb + 4207680);         // 2435*16 = 155,840
    float4 *pos4 = (float4 *)(wsb + 4363520);      // 32768*16 = 524,288
    double *tbuf = (double *)(wsb + 4887808);      // 4 MB (small-Q chunks)
    // B3-tail dot scalar: last 8B of the tbuf region. Never written by any
    // t_kernel: B1's largest chunk writes 91*5760*8 = 4,193,280 <= 4MB-1024;
    // B2/B3 write far less. Zeroed by prep_kernel at stream start.
    double *dsc  = (double *)(wsb + 9082112 - 8);
    if (ws_size < 9082112) return;

    prep_kernel<<<128, 256, 0, stream>>>(posf, pos4, dsc);

    // Large Q: selection-only kNN + parallel geom kernel (r7 win).
    // Small Q: geometry fused in-block (launch overhead > parallel tail).
    auto knng = [&](int Q, int S, int k) {
        if (S <= 64) {
            knngs_kernel<<<Q, 64, 0, stream>>>(pos4, posf, S, k, idx, rrot);
        } else if (Q >= 512) {
            knng16_kernel<0><<<Q, 256, 0, stream>>>(pos4, posf, S, idx, rrot);
            geom_kernel<<<(Q + 255) / 256, 256, 0, stream>>>(posf, idx, Q, k, rrot);
        } else {
            knng16_kernel<1><<<Q, 256, 0, stream>>>(pos4, posf, S, idx, rrot);
        }
    };

    // fused per-query path (B0-L1)
    auto conv = [&](int Q, int S, int k, const double *fin64, const float *fin32, int C,
                    const float *w, const float *bias, int O, double *fout) {
        knng(Q, S, k);
        size_t dyn = (size_t)(16 + 9) * C * sizeof(double);
        feat_kernel<<<Q, 256, dyn, stream>>>(rrot, idx, k, fin64, fin32, C, w, bias, O, fout);
    };

    // specialized C=64/O=64 path (B0-L2)
    auto conv64 = [&](int Q, int S, const double *fin, const float *w,
                      const float *bias, double *fout) {
        knng(Q, S, 16);
        feat64_kernel<<<(Q + 1) / 2, 256, 0, stream>>>(rrot, idx, fin, w, bias, Q, fout);
    };

    // split t + K-parallel GEMM path (small Q) -- K-split grid is essential.
    // fout is left as RAW atomic acc; the layer's bias+relu is applied by
    // the consumer (next t_kernel's fbias, or resid64f/rvdot).
    auto conv2 = [&](int Q, int S, int k, const double *fin, const float *fbias,
                     int C, const float *w, int O, double *fout,
                     int ksplit, bool skip_knn) {
        if (!skip_knn) knng(Q, S, k);
        int K = 45 * C;
        int qc = 4194304 / (K * 8);
        if (qc > Q) qc = Q;
        int OT = O < 256 ? O : 256;
        int qpb = 256 / OT;
        int kchunk = (((K + ksplit - 1) / ksplit) + 7) & ~7;
        for (int q0 = 0; q0 < Q; q0 += qc) {
            int qn = min(qc, Q - q0);
            dim3 gt(qn, 5);
            t_kernel<<<gt, 256, (size_t)16 * C * sizeof(double), stream>>>(
                rrot, idx, k, fin, fbias, C, q0, tbuf, fout, O);
            dim3 g(O / OT, (qn + qpb - 1) / qpb, ksplit);
            gemm_kernel<<<g, 256, 0, stream>>>(tbuf, w, K, O, q0, q0 + qn, kchunk, fout);
        }
    };

    // Block 0 (Q=2435)
    conv(2435, 32768, 16, nullptr, chanf, 4, W[1], B[1], 64, B1);
    conv64(2435, 2435, B1, W[2], B[2], B2);
    resid0_kernel<<<(2435 * 64 + 255) / 256, 256, 0, stream>>>(chanf, P[1], B2, B3);
    // Block 1 (Q=181)
    // L3 kNN == rows 0..180 of B0-L2's knn(pos[:2435],pos[:2435]) -> skip.
    conv2(181, 2435, 16, B3, nullptr, 64, W[3], 128, B1, 48, true);
    // L4: fin = L3's raw acc -> fbias = B[3].
    conv2(181, 181, 16, B1, B[3], 128, W[4], 128, B2, 48, false);
    resid64f_kernel<<<(181 * 128 + 255) / 256, 256, 0, stream>>>(
        B[4], B2, B3, 64, P[2], 181, 128, B1);
    // Block 2 (Q=13)
    // L5 kNN == rows 0..12 of B1-L4's knn(pos[:181],pos[:181]) -> skip.
    conv2(13, 181, 16, B1, nullptr, 128, W[5], 256, B2, 160, true);
    // L6: fin = L5's raw acc -> fbias = B[5].
    conv2(13, 13, 13, B2, B[5], 256, W[6], 256, B3, 160, false);
    resid64f_kernel<<<(13 * 256 + 255) / 256, 256, 0, stream>>>(
        B[6], B3, B1, 128, P[3], 13, 256, B2);
    // Block 3 (Q=1)
    // L7 kNN == row 0 of B2-L6's knn(pos[:13],pos[:13],k=13) -> skip.
    conv2(1, 13, 13, B2, nullptr, 256, W[7], 512, B1, 320, true);
    // Parallel B3 tail: rvdot (16 blocks) + scalar head.
    rvdot_kernel<<<16, 256, 0, stream>>>(B[7], B1, B2, 256, P[4], hw, dsc);
    outhead_kernel<<<1, 64, 0, stream>>>(dsc, hb, (float *)d_out);
}